// Round 1
// baseline (1245.845 us; speedup 1.0000x reference)
//
#include <hip/hip_runtime.h>
#include <cstddef>

// Problem constants (match reference)
#define Bb   4
#define CI   128
#define CO   128
#define Hh   128
#define Ww   128
#define HW   (Hh*Ww)
#define NOFF 18      // 2*K*K
#define NTAP 9       // K*K

// ---------------------------------------------------------------------------
// K0: transpose x NCHW -> NHWC (per batch: C x HW matrix -> HW x C)
// ---------------------------------------------------------------------------
__global__ __launch_bounds__(256) void k_transpose(const float* __restrict__ x,
                                                   float* __restrict__ xt) {
    __shared__ float tile[32][33];
    int b  = blockIdx.z;
    int c0 = blockIdx.y * 32;
    int p0 = blockIdx.x * 32;      // hw offset
    int tx = threadIdx.x;          // 0..31
    int ty = threadIdx.y;          // 0..7
    const float* xb  = x  + (size_t)b * CI * HW;
    float*       xtb = xt + (size_t)b * HW * CI;
#pragma unroll
    for (int i = 0; i < 4; ++i) {
        int c = c0 + ty + 8 * i;
        tile[ty + 8 * i][tx] = xb[(size_t)c * HW + p0 + tx];
    }
    __syncthreads();
#pragma unroll
    for (int i = 0; i < 4; ++i) {
        int p = p0 + ty + 8 * i;
        xtb[(size_t)p * CI + c0 + tx] = tile[tx][ty + 8 * i];
    }
}

// ---------------------------------------------------------------------------
// K0b: weight layout transforms
//  woff_t[((oc*3+ky)*3+kx)*128 + c] = w_off[(oc*128+c)*9 + ky*3+kx]
//  w2[(kk*128+c)*128 + o]          = w_main[(o*128+c)*9 + kk]
// ---------------------------------------------------------------------------
__global__ __launch_bounds__(256) void k_weights(const float* __restrict__ w_off,
                                                 const float* __restrict__ w_main,
                                                 float* __restrict__ woff_t,
                                                 float* __restrict__ w2) {
    int idx = blockIdx.x * 256 + threadIdx.x;
    int stride = gridDim.x * 256;
    for (int i = idx; i < NOFF * 9 * CI; i += stride) {
        int c  = i & 127;
        int kk = (i >> 7) % 9;
        int oc = i / (9 * CI);
        woff_t[i] = w_off[(oc * CI + c) * 9 + kk];
    }
    for (int i = idx; i < 9 * CI * CO; i += stride) {
        int o  = i & 127;
        int c  = (i >> 7) & 127;
        int kk = i >> 14;
        w2[i] = w_main[(o * CI + c) * 9 + kk];
    }
}

// ---------------------------------------------------------------------------
// K1: offset conv (128->18, 3x3, pad 1) + per-pixel cumsum + sample coords.
// One block = 32-pixel row segment. Patch staged in LDS (stride 132 to avoid
// bank conflicts: 4 distinct px per wave -> 4 distinct banks).
// ---------------------------------------------------------------------------
#define PSTR 132
__global__ __launch_bounds__(256) void k_offsets(const float* __restrict__ xt,
                                                 const float* __restrict__ woff_t,
                                                 const float* __restrict__ b_off,
                                                 float2* __restrict__ coords) {
    __shared__ float patch[3 * 34 * PSTR];   // 53,856 B
    __shared__ float raw[32][19];
    int blk = blockIdx.x;
    int wt  = blk & 3;
    int h   = (blk >> 2) & 127;
    int b   = blk >> 9;
    int w0  = wt * 32;
    int tid = threadIdx.x;

    // load 3 rows x 34 cols x 128 ch patch (zero outside image)
    for (int i = tid; i < 3 * 34 * CI; i += 256) {
        int c   = i & 127;
        int col = (i >> 7) % 34;
        int r   = i / (34 * CI);
        int gy  = h - 1 + r;
        int gx  = w0 - 1 + col;
        float v = 0.f;
        if (gy >= 0 && gy < Hh && gx >= 0 && gx < Ww)
            v = xt[(((size_t)b * Hh + gy) * Ww + gx) * CI + c];
        patch[(r * 34 + col) * PSTR + c] = v;
    }
    __syncthreads();

    // conv: 32 px * 18 oc outputs
    for (int oidx = tid; oidx < 32 * NOFF; oidx += 256) {
        int px = oidx / NOFF;
        int oc = oidx % NOFF;
        float acc = b_off[oc];
#pragma unroll
        for (int ky = 0; ky < 3; ++ky) {
#pragma unroll
            for (int kx = 0; kx < 3; ++kx) {
                const float* pp = &patch[(ky * 34 + px + kx) * PSTR];
                const float* wp = &woff_t[((oc * 3 + ky) * 3 + kx) * CI];
                for (int c = 0; c < CI; c += 4) {
                    float4 pv = *(const float4*)(pp + c);
                    float4 wv = *(const float4*)(wp + c);
                    acc += pv.x * wv.x + pv.y * wv.y + pv.z * wv.z + pv.w * wv.w;
                }
            }
        }
        raw[px][oc] = acc;
    }
    __syncthreads();

    // cumsum + coordinate math, one (px, tap) per thread-task
    for (int i = tid; i < 32 * NTAP; i += 256) {
        int px = i / NTAP;
        int t  = i % NTAP;
        int ki = t / 3, kj = t % 3;
        float offx = 0.f, offy = 0.f;
        for (int q = 0; q <= ki; ++q) offx += raw[px][q * 6 + kj * 2 + 0];
        for (int q = 0; q <= kj; ++q) offy += raw[px][ki * 6 + q * 2 + 1];
        int wg = w0 + px;
        float xg = -1.0f + 2.0f * (float)wg / 127.0f;
        float yg = -1.0f + 2.0f * (float)h  / 127.0f;
        float gx = xg + offx;
        float gy = yg + offy;
        float ix = ((gx + 1.0f) * (float)Ww - 1.0f) * 0.5f;
        float iy = ((gy + 1.0f) * (float)Hh - 1.0f) * 0.5f;
        coords[(((size_t)b * Hh + h) * Ww + wg) * NTAP + t] = make_float2(ix, iy);
    }
}

// ---------------------------------------------------------------------------
// K2: fused bilinear sampling + main conv (GEMM per 16-pixel tile) + bias.
// 3 tap-group chunks of j=384; sampling is wave-per-(px,tap) with lane=c.
// GEMM register tile: 2 px x 4 o per thread; w2 reads lane-coalesced float4.
// ---------------------------------------------------------------------------
__global__ __launch_bounds__(256) void k_main(const float* __restrict__ xt,
                                              const float2* __restrict__ coords,
                                              const float* __restrict__ w2,
                                              const float* __restrict__ b_main,
                                              float* __restrict__ out) {
    __shared__ float smem[16 * 384];   // 24,576 B (reused for epilogue)
    int blk  = blockIdx.x;
    int wt   = blk & 7;
    int h    = (blk >> 3) & 127;
    int b    = blk >> 10;
    int w0   = wt * 16;
    int tid  = threadIdx.x;
    int lane = tid & 63;
    int wave = tid >> 6;
    int og   = tid & 31;   // o = 4*og + u
    int pg   = tid >> 5;   // px in {pg, pg+8}

    float acc[2][4] = {{0.f, 0.f, 0.f, 0.f}, {0.f, 0.f, 0.f, 0.f}};
    const float* xtb = xt + (size_t)b * HW * CI;

    for (int g = 0; g < 3; ++g) {
        // ---- sampling: 16 px * 3 taps = 48 tasks, one wave each ----
        for (int task = wave; task < 48; task += 4) {
            int px   = task / 3;
            int tloc = task % 3;
            int t    = g * 3 + tloc;
            float2 co = coords[(((size_t)b * Hh + h) * Ww + w0 + px) * NTAP + t];
            float ix = co.x, iy = co.y;
            float fx0 = floorf(ix), fy0 = floorf(iy);
            int x0 = (int)fx0, y0 = (int)fy0;
            int x1 = x0 + 1,   y1 = y0 + 1;
            float wx1 = ix - fx0, wy1 = iy - fy0;
            float wx0 = 1.f - wx1, wy0 = 1.f - wy1;
            bool vx0 = (x0 >= 0) & (x0 < Ww);
            bool vx1 = (x1 >= 0) & (x1 < Ww);
            bool vy0 = (y0 >= 0) & (y0 < Hh);
            bool vy1 = (y1 >= 0) & (y1 < Hh);
            int cx0 = min(max(x0, 0), Ww - 1), cx1 = min(max(x1, 0), Ww - 1);
            int cy0 = min(max(y0, 0), Hh - 1), cy1 = min(max(y1, 0), Hh - 1);
            float w00 = (vy0 && vx0) ? wy0 * wx0 : 0.f;
            float w01 = (vy0 && vx1) ? wy0 * wx1 : 0.f;
            float w10 = (vy1 && vx0) ? wy1 * wx0 : 0.f;
            float w11 = (vy1 && vx1) ? wy1 * wx1 : 0.f;
            const float* r0 = xtb + (size_t)cy0 * Ww * CI;
            const float* r1 = xtb + (size_t)cy1 * Ww * CI;
#pragma unroll
            for (int half = 0; half < 2; ++half) {
                int c = lane + 64 * half;
                float v = w00 * r0[cx0 * CI + c] + w01 * r0[cx1 * CI + c]
                        + w10 * r1[cx0 * CI + c] + w11 * r1[cx1 * CI + c];
                smem[px * 384 + tloc * 128 + c] = v;
            }
        }
        __syncthreads();

        // ---- partial GEMM over this chunk's 384 j values ----
        const float* wgp = w2 + (size_t)g * 384 * CO;
        int p0 = pg, p1 = pg + 8;
        for (int j = 0; j < 384; j += 4) {
            float4 s0 = *(const float4*)&smem[p0 * 384 + j];
            float4 s1 = *(const float4*)&smem[p1 * 384 + j];
#pragma unroll
            for (int u = 0; u < 4; ++u) {
                float4 wv = *(const float4*)&wgp[(size_t)(j + u) * CO + 4 * og];
                float sa = (&s0.x)[u];
                float sb = (&s1.x)[u];
                acc[0][0] += sa * wv.x; acc[0][1] += sa * wv.y;
                acc[0][2] += sa * wv.z; acc[0][3] += sa * wv.w;
                acc[1][0] += sb * wv.x; acc[1][1] += sb * wv.y;
                acc[1][2] += sb * wv.z; acc[1][3] += sb * wv.w;
            }
        }
        __syncthreads();
    }

    // ---- epilogue: transpose through LDS for coalesced stores ----
    float* sout = smem;   // [128][17]
#pragma unroll
    for (int pp = 0; pp < 2; ++pp) {
        int px = pg + 8 * pp;
#pragma unroll
        for (int u = 0; u < 4; ++u) {
            sout[(4 * og + u) * 17 + px] = acc[pp][u];
        }
    }
    __syncthreads();
    float* ob = out + ((size_t)b * CO * Hh + h) * Ww;
    for (int i = tid; i < CO * 16; i += 256) {
        int o  = i >> 4;
        int px = i & 15;
        ob[(size_t)o * HW + w0 + px] = sout[o * 17 + px] + b_main[o];
    }
}

// ---------------------------------------------------------------------------
extern "C" void kernel_launch(void* const* d_in, const int* in_sizes, int n_in,
                              void* d_out, int out_size, void* d_ws, size_t ws_size,
                              hipStream_t stream) {
    const float* x      = (const float*)d_in[0];   // [4][128][128][128]
    const float* w_off  = (const float*)d_in[1];   // [18][128][3][3]
    const float* b_off  = (const float*)d_in[2];   // [18]
    const float* w_main = (const float*)d_in[3];   // [128][128][3][3]
    const float* b_main = (const float*)d_in[4];   // [128]
    float* out = (float*)d_out;

    // workspace layout (floats): xt | coords | woff_t | w2  (~39 MB total)
    float*  ws     = (float*)d_ws;
    float*  xt     = ws;                                   // 8,388,608 floats
    float2* coords = (float2*)(ws + (size_t)Bb * HW * CI); // 589,824 float2
    float*  woff_t = ws + (size_t)Bb * HW * CI + (size_t)Bb * HW * NTAP * 2;
    float*  w2     = woff_t + NOFF * 9 * CI;

    k_transpose<<<dim3(HW / 32, CI / 32, Bb), dim3(32, 8), 0, stream>>>(x, xt);
    k_weights<<<576, 256, 0, stream>>>(w_off, w_main, woff_t, w2);
    k_offsets<<<Bb * Hh * (Ww / 32), 256, 0, stream>>>(xt, woff_t, b_off, coords);
    k_main<<<Bb * Hh * (Ww / 16), 256, 0, stream>>>(xt, coords, w2, b_main, out);
}

// Round 3
// 787.421 us; speedup vs baseline: 1.5822x; 1.5822x over previous
//
#include <hip/hip_runtime.h>
#include <cstddef>

// Problem constants (match reference)
#define Bb   4
#define CI   128
#define CO   128
#define Hh   128
#define Ww   128
#define HW   (Hh*Ww)
#define NOFF 18      // 2*K*K
#define NTAP 9       // K*K

// ---------------------------------------------------------------------------
// K0: transpose x NCHW -> NHWC (per batch: C x HW matrix -> HW x C)
// ---------------------------------------------------------------------------
__global__ __launch_bounds__(256) void k_transpose(const float* __restrict__ x,
                                                   float* __restrict__ xt) {
    __shared__ float tile[32][33];
    int b  = blockIdx.z;
    int c0 = blockIdx.y * 32;
    int p0 = blockIdx.x * 32;      // hw offset
    int tx = threadIdx.x;          // 0..31
    int ty = threadIdx.y;          // 0..7
    const float* xb  = x  + (size_t)b * CI * HW;
    float*       xtb = xt + (size_t)b * HW * CI;
#pragma unroll
    for (int i = 0; i < 4; ++i) {
        int c = c0 + ty + 8 * i;
        tile[ty + 8 * i][tx] = xb[(size_t)c * HW + p0 + tx];
    }
    __syncthreads();
#pragma unroll
    for (int i = 0; i < 4; ++i) {
        int p = p0 + ty + 8 * i;
        xtb[(size_t)p * CI + c0 + tx] = tile[tx][ty + 8 * i];
    }
}

// ---------------------------------------------------------------------------
// K0b: weight layout transforms
//  woff_t[((oc*3+ky)*3+kx)*128 + c] = w_off[(oc*128+c)*9 + ky*3+kx]
//  w2[(kk*128+c)*128 + o]          = w_main[(o*128+c)*9 + kk]
// ---------------------------------------------------------------------------
__global__ __launch_bounds__(256) void k_weights(const float* __restrict__ w_off,
                                                 const float* __restrict__ w_main,
                                                 float* __restrict__ woff_t,
                                                 float* __restrict__ w2) {
    int idx = blockIdx.x * 256 + threadIdx.x;
    int stride = gridDim.x * 256;
    for (int i = idx; i < NOFF * 9 * CI; i += stride) {
        int c  = i & 127;
        int kk = (i >> 7) % 9;
        int oc = i / (9 * CI);
        woff_t[i] = w_off[(oc * CI + c) * 9 + kk];
    }
    for (int i = idx; i < 9 * CI * CO; i += stride) {
        int o  = i & 127;
        int c  = (i >> 7) & 127;
        int kk = i >> 14;
        w2[i] = w_main[(o * CI + c) * 9 + kk];
    }
}

// ---------------------------------------------------------------------------
// K1: offset conv (128->18, 3x3, pad 1) + per-pixel cumsum + sample coords.
// One block = 16-pixel row segment (LDS ~29.7KB -> 5 blocks/CU, 62% occ).
// Task map: oc = oidx>>4 (wave-broadcast weight rows), px = oidx&15.
// ---------------------------------------------------------------------------
#define PSTR 132
__global__ __launch_bounds__(256) void k_offsets(const float* __restrict__ xt,
                                                 const float* __restrict__ woff_t,
                                                 const float* __restrict__ b_off,
                                                 float2* __restrict__ coords) {
    __shared__ float patch[3 * 18 * PSTR];   // 28,512 B
    __shared__ float raw[16][19];            //  1,216 B
    int blk = blockIdx.x;
    int wt  = blk & 7;
    int h   = (blk >> 3) & 127;
    int b   = blk >> 10;
    int w0  = wt * 16;
    int tid = threadIdx.x;

    // load 3 rows x 18 cols x 128 ch patch (zero outside image)
    for (int i = tid; i < 3 * 18 * CI; i += 256) {
        int c   = i & 127;
        int col = (i >> 7) % 18;
        int r   = i / (18 * CI);
        int gy  = h - 1 + r;
        int gx  = w0 - 1 + col;
        float v = 0.f;
        if (gy >= 0 && gy < Hh && gx >= 0 && gx < Ww)
            v = xt[(((size_t)b * Hh + gy) * Ww + gx) * CI + c];
        patch[(r * 18 + col) * PSTR + c] = v;
    }
    __syncthreads();

    // conv: 16 px * 18 oc outputs; oc slow (weight rows broadcast in-wave)
    for (int oidx = tid; oidx < 16 * NOFF; oidx += 256) {
        int px = oidx & 15;
        int oc = oidx >> 4;
        float acc0 = b_off[oc], acc1 = 0.f;
#pragma unroll
        for (int ky = 0; ky < 3; ++ky) {
#pragma unroll
            for (int kx = 0; kx < 3; ++kx) {
                const float* pp = &patch[(ky * 18 + px + kx) * PSTR];
                const float* wp = &woff_t[((oc * 3 + ky) * 3 + kx) * CI];
#pragma unroll 4
                for (int c = 0; c < CI; c += 8) {
                    float4 p0 = *(const float4*)(pp + c);
                    float4 w0v = *(const float4*)(wp + c);
                    float4 p1 = *(const float4*)(pp + c + 4);
                    float4 w1v = *(const float4*)(wp + c + 4);
                    acc0 += (p0.x * w0v.x + p0.y * w0v.y)
                          + (p0.z * w0v.z + p0.w * w0v.w);
                    acc1 += (p1.x * w1v.x + p1.y * w1v.y)
                          + (p1.z * w1v.z + p1.w * w1v.w);
                }
            }
        }
        raw[px][oc] = acc0 + acc1;
    }
    __syncthreads();

    // cumsum + coordinate math, one (px, tap) per thread-task
    for (int i = tid; i < 16 * NTAP; i += 256) {
        int px = i / NTAP;
        int t  = i % NTAP;
        int ki = t / 3, kj = t % 3;
        float offx = 0.f, offy = 0.f;
        for (int q = 0; q <= ki; ++q) offx += raw[px][q * 6 + kj * 2 + 0];
        for (int q = 0; q <= kj; ++q) offy += raw[px][ki * 6 + q * 2 + 1];
        int wg = w0 + px;
        float xg = -1.0f + 2.0f * (float)wg / 127.0f;
        float yg = -1.0f + 2.0f * (float)h  / 127.0f;
        float gx = xg + offx;
        float gy = yg + offy;
        float ix = ((gx + 1.0f) * (float)Ww - 1.0f) * 0.5f;
        float iy = ((gy + 1.0f) * (float)Hh - 1.0f) * 0.5f;
        coords[(((size_t)b * Hh + h) * Ww + wg) * NTAP + t] = make_float2(ix, iy);
    }
}

// ---------------------------------------------------------------------------
// K2: fused bilinear sampling + main conv (GEMM per 16-pixel tile) + bias.
// 3 tap-group chunks of j=384; sampling is wave-per-(px,tap) with lane=c.
// GEMM register tile: 2 px x 4 o per thread; w2 reads lane-coalesced float4.
// ---------------------------------------------------------------------------
__global__ __launch_bounds__(256) void k_main(const float* __restrict__ xt,
                                              const float2* __restrict__ coords,
                                              const float* __restrict__ w2,
                                              const float* __restrict__ b_main,
                                              float* __restrict__ out) {
    __shared__ float smem[16 * 384];   // 24,576 B (reused for epilogue)
    int blk  = blockIdx.x;
    int wt   = blk & 7;
    int h    = (blk >> 3) & 127;
    int b    = blk >> 10;
    int w0   = wt * 16;
    int tid  = threadIdx.x;
    int lane = tid & 63;
    int wave = tid >> 6;
    int og   = tid & 31;   // o = 4*og + u
    int pg   = tid >> 5;   // px in {pg, pg+8}

    float acc[2][4] = {{0.f, 0.f, 0.f, 0.f}, {0.f, 0.f, 0.f, 0.f}};
    const float* xtb = xt + (size_t)b * HW * CI;

    for (int g = 0; g < 3; ++g) {
        // ---- sampling: 16 px * 3 taps = 48 tasks, one wave each ----
        for (int task = wave; task < 48; task += 4) {
            int px   = task / 3;
            int tloc = task % 3;
            int t    = g * 3 + tloc;
            float2 co = coords[(((size_t)b * Hh + h) * Ww + w0 + px) * NTAP + t];
            float ix = co.x, iy = co.y;
            float fx0 = floorf(ix), fy0 = floorf(iy);
            int x0 = (int)fx0, y0 = (int)fy0;
            int x1 = x0 + 1,   y1 = y0 + 1;
            float wx1 = ix - fx0, wy1 = iy - fy0;
            float wx0 = 1.f - wx1, wy0 = 1.f - wy1;
            bool vx0 = (x0 >= 0) & (x0 < Ww);
            bool vx1 = (x1 >= 0) & (x1 < Ww);
            bool vy0 = (y0 >= 0) & (y0 < Hh);
            bool vy1 = (y1 >= 0) & (y1 < Hh);
            int cx0 = min(max(x0, 0), Ww - 1), cx1 = min(max(x1, 0), Ww - 1);
            int cy0 = min(max(y0, 0), Hh - 1), cy1 = min(max(y1, 0), Hh - 1);
            float w00 = (vy0 && vx0) ? wy0 * wx0 : 0.f;
            float w01 = (vy0 && vx1) ? wy0 * wx1 : 0.f;
            float w10 = (vy1 && vx0) ? wy1 * wx0 : 0.f;
            float w11 = (vy1 && vx1) ? wy1 * wx1 : 0.f;
            const float* r0 = xtb + (size_t)cy0 * Ww * CI;
            const float* r1 = xtb + (size_t)cy1 * Ww * CI;
#pragma unroll
            for (int half = 0; half < 2; ++half) {
                int c = lane + 64 * half;
                float v = w00 * r0[cx0 * CI + c] + w01 * r0[cx1 * CI + c]
                        + w10 * r1[cx0 * CI + c] + w11 * r1[cx1 * CI + c];
                smem[px * 384 + tloc * 128 + c] = v;
            }
        }
        __syncthreads();

        // ---- partial GEMM over this chunk's 384 j values ----
        const float* wgp = w2 + (size_t)g * 384 * CO;
        int p0 = pg, p1 = pg + 8;
        for (int j = 0; j < 384; j += 4) {
            float4 s0 = *(const float4*)&smem[p0 * 384 + j];
            float4 s1 = *(const float4*)&smem[p1 * 384 + j];
#pragma unroll
            for (int u = 0; u < 4; ++u) {
                float4 wv = *(const float4*)&wgp[(size_t)(j + u) * CO + 4 * og];
                float sa = (&s0.x)[u];
                float sb = (&s1.x)[u];
                acc[0][0] += sa * wv.x; acc[0][1] += sa * wv.y;
                acc[0][2] += sa * wv.z; acc[0][3] += sa * wv.w;
                acc[1][0] += sb * wv.x; acc[1][1] += sb * wv.y;
                acc[1][2] += sb * wv.z; acc[1][3] += sb * wv.w;
            }
        }
        __syncthreads();
    }

    // ---- epilogue: transpose through LDS for coalesced stores ----
    float* sout = smem;   // [128][17]
#pragma unroll
    for (int pp = 0; pp < 2; ++pp) {
        int px = pg + 8 * pp;
#pragma unroll
        for (int u = 0; u < 4; ++u) {
            sout[(4 * og + u) * 17 + px] = acc[pp][u];
        }
    }
    __syncthreads();
    float* ob = out + ((size_t)b * CO * Hh + h) * Ww;
    for (int i = tid; i < CO * 16; i += 256) {
        int o  = i >> 4;
        int px = i & 15;
        ob[(size_t)o * HW + w0 + px] = sout[o * 17 + px] + b_main[o];
    }
}

// ---------------------------------------------------------------------------
extern "C" void kernel_launch(void* const* d_in, const int* in_sizes, int n_in,
                              void* d_out, int out_size, void* d_ws, size_t ws_size,
                              hipStream_t stream) {
    const float* x      = (const float*)d_in[0];   // [4][128][128][128]
    const float* w_off  = (const float*)d_in[1];   // [18][128][3][3]
    const float* b_off  = (const float*)d_in[2];   // [18]
    const float* w_main = (const float*)d_in[3];   // [128][128][3][3]
    const float* b_main = (const float*)d_in[4];   // [128]
    float* out = (float*)d_out;

    // workspace layout (floats): xt | coords | woff_t | w2  (~39 MB total)
    float*  ws     = (float*)d_ws;
    float*  xt     = ws;                                   // 8,388,608 floats
    float2* coords = (float2*)(ws + (size_t)Bb * HW * CI); // 589,824 float2
    float*  woff_t = ws + (size_t)Bb * HW * CI + (size_t)Bb * HW * NTAP * 2;
    float*  w2     = woff_t + NOFF * 9 * CI;

    k_transpose<<<dim3(HW / 32, CI / 32, Bb), dim3(32, 8), 0, stream>>>(x, xt);
    k_weights<<<576, 256, 0, stream>>>(w_off, w_main, woff_t, w2);
    k_offsets<<<Bb * Hh * (Ww / 16), 256, 0, stream>>>(xt, woff_t, b_off, coords);
    k_main<<<Bb * Hh * (Ww / 16), 256, 0, stream>>>(xt, coords, w2, b_main, out);
}

// Round 5
// 625.513 us; speedup vs baseline: 1.9917x; 1.2588x over previous
//
#include <hip/hip_runtime.h>
#include <cstddef>

// Problem constants (match reference)
#define Bb   4
#define CI   128
#define CO   128
#define Hh   128
#define Ww   128
#define HW   (Hh*Ww)
#define NOFF 18      // 2*K*K
#define NTAP 9       // K*K
#define KTOT (NTAP*CI)   // 1152

typedef short short8 __attribute__((ext_vector_type(8)));
typedef float floatx4 __attribute__((ext_vector_type(4)));

// bf16 RNE split helpers (no NaN/inf in this data)
__device__ inline unsigned short bf16_rne_bits(float f) {
    unsigned u = __float_as_uint(f);
    unsigned r = u + 0x7FFFu + ((u >> 16) & 1u);
    return (unsigned short)(r >> 16);
}
__device__ inline float bf16_bits_to_f32(unsigned short h) {
    return __uint_as_float((unsigned)h << 16);
}

// ---------------------------------------------------------------------------
// K0: transpose x NCHW -> NHWC (per batch: C x HW matrix -> HW x C)
// ---------------------------------------------------------------------------
__global__ __launch_bounds__(256) void k_transpose(const float* __restrict__ x,
                                                   float* __restrict__ xt) {
    __shared__ float tile[32][33];
    int b  = blockIdx.z;
    int c0 = blockIdx.y * 32;
    int p0 = blockIdx.x * 32;      // hw offset
    int tx = threadIdx.x;          // 0..31
    int ty = threadIdx.y;          // 0..7
    const float* xb  = x  + (size_t)b * CI * HW;
    float*       xtb = xt + (size_t)b * HW * CI;
#pragma unroll
    for (int i = 0; i < 4; ++i) {
        int c = c0 + ty + 8 * i;
        tile[ty + 8 * i][tx] = xb[(size_t)c * HW + p0 + tx];
    }
    __syncthreads();
#pragma unroll
    for (int i = 0; i < 4; ++i) {
        int p = p0 + ty + 8 * i;
        xtb[(size_t)p * CI + c0 + tx] = tile[tx][ty + 8 * i];
    }
}

// ---------------------------------------------------------------------------
// K0b: weight layout transforms
//  woff_t[((oc*3+ky)*3+kx)*128 + c] = w_off[(oc*128+c)*9 + ky*3+kx]   (fp32)
//  wt_hi/wt_lo[o*1152 + tap*128 + c] = bf16 split of w_main[(o*128+c)*9 + tap]
// ---------------------------------------------------------------------------
__global__ __launch_bounds__(256) void k_weights(const float* __restrict__ w_off,
                                                 const float* __restrict__ w_main,
                                                 float* __restrict__ woff_t,
                                                 unsigned short* __restrict__ wt_hi,
                                                 unsigned short* __restrict__ wt_lo) {
    int idx = blockIdx.x * 256 + threadIdx.x;
    int stride = gridDim.x * 256;
    for (int i = idx; i < NOFF * 9 * CI; i += stride) {
        int c  = i & 127;
        int kk = (i >> 7) % 9;
        int oc = i / (9 * CI);
        woff_t[i] = w_off[(oc * CI + c) * 9 + kk];
    }
    for (int i = idx; i < CO * KTOT; i += stride) {
        int o   = i / KTOT;
        int rem = i % KTOT;
        int tap = rem >> 7;
        int c   = rem & 127;
        float f = w_main[(o * CI + c) * 9 + tap];
        unsigned short hb = bf16_rne_bits(f);
        float lo = f - bf16_bits_to_f32(hb);
        wt_hi[i] = hb;
        wt_lo[i] = bf16_rne_bits(lo);
    }
}

// ---------------------------------------------------------------------------
// K1: offset conv (128->18, 3x3, pad 1) + per-pixel cumsum + sample coords.
// One block = 16-pixel row segment (LDS ~29.7KB -> 5 blocks/CU).
// Task map: oc = oidx>>4 (wave-broadcast weight rows), px = oidx&15.
// ---------------------------------------------------------------------------
#define PSTR 132
__global__ __launch_bounds__(256) void k_offsets(const float* __restrict__ xt,
                                                 const float* __restrict__ woff_t,
                                                 const float* __restrict__ b_off,
                                                 float2* __restrict__ coords) {
    __shared__ float patch[3 * 18 * PSTR];   // 28,512 B
    __shared__ float raw[16][19];            //  1,216 B
    int blk = blockIdx.x;
    int wt  = blk & 7;
    int h   = (blk >> 3) & 127;
    int b   = blk >> 10;
    int w0  = wt * 16;
    int tid = threadIdx.x;

    for (int i = tid; i < 3 * 18 * CI; i += 256) {
        int c   = i & 127;
        int col = (i >> 7) % 18;
        int r   = i / (18 * CI);
        int gy  = h - 1 + r;
        int gx  = w0 - 1 + col;
        float v = 0.f;
        if (gy >= 0 && gy < Hh && gx >= 0 && gx < Ww)
            v = xt[(((size_t)b * Hh + gy) * Ww + gx) * CI + c];
        patch[(r * 18 + col) * PSTR + c] = v;
    }
    __syncthreads();

    for (int oidx = tid; oidx < 16 * NOFF; oidx += 256) {
        int px = oidx & 15;
        int oc = oidx >> 4;
        float acc0 = b_off[oc], acc1 = 0.f;
#pragma unroll
        for (int ky = 0; ky < 3; ++ky) {
#pragma unroll
            for (int kx = 0; kx < 3; ++kx) {
                const float* pp = &patch[(ky * 18 + px + kx) * PSTR];
                const float* wp = &woff_t[((oc * 3 + ky) * 3 + kx) * CI];
#pragma unroll 4
                for (int c = 0; c < CI; c += 8) {
                    float4 p0 = *(const float4*)(pp + c);
                    float4 w0v = *(const float4*)(wp + c);
                    float4 p1 = *(const float4*)(pp + c + 4);
                    float4 w1v = *(const float4*)(wp + c + 4);
                    acc0 += (p0.x * w0v.x + p0.y * w0v.y)
                          + (p0.z * w0v.z + p0.w * w0v.w);
                    acc1 += (p1.x * w1v.x + p1.y * w1v.y)
                          + (p1.z * w1v.z + p1.w * w1v.w);
                }
            }
        }
        raw[px][oc] = acc0 + acc1;
    }
    __syncthreads();

    for (int i = tid; i < 16 * NTAP; i += 256) {
        int px = i / NTAP;
        int t  = i % NTAP;
        int ki = t / 3, kj = t % 3;
        float offx = 0.f, offy = 0.f;
        for (int q = 0; q <= ki; ++q) offx += raw[px][q * 6 + kj * 2 + 0];
        for (int q = 0; q <= kj; ++q) offy += raw[px][ki * 6 + q * 2 + 1];
        int wg = w0 + px;
        float xg = -1.0f + 2.0f * (float)wg / 127.0f;
        float yg = -1.0f + 2.0f * (float)h  / 127.0f;
        float gx = xg + offx;
        float gy = yg + offy;
        float ix = ((gx + 1.0f) * (float)Ww - 1.0f) * 0.5f;
        float iy = ((gy + 1.0f) * (float)Hh - 1.0f) * 0.5f;
        coords[(((size_t)b * Hh + h) * Ww + wg) * NTAP + t] = make_float2(ix, iy);
    }
}

// ---------------------------------------------------------------------------
// K2: fused bilinear sampling + split-bf16 MFMA main conv + bias.
// Block = 32 px x 128 o, 4 waves (2m x 2n). Per tap: sample -> LDS bf16
// hi/lo tiles [32px][128k] (XOR-swizzled), then 4 K-steps of
// mfma_f32_16x16x32_bf16 with 3 products (hi*hi, hi*lo, lo*hi).
// A frag: row=lane&15, k=(lane>>4)*8+j. C/D: col=lane&15, row=(lane>>4)*4+r.
// ---------------------------------------------------------------------------
__global__ __launch_bounds__(256) void k_main(const float* __restrict__ xt,
                                              const float2* __restrict__ coords,
                                              const unsigned short* __restrict__ wt_hi,
                                              const unsigned short* __restrict__ wt_lo,
                                              const float* __restrict__ b_main,
                                              float* __restrict__ out) {
    // A_hi words [0,8K), A_lo [8K,16K); epilogue reuses as f32 [128][33]
    __shared__ __align__(16) char lds[17024];
    unsigned int* a_hi_w = (unsigned int*)lds;
    unsigned int* a_lo_w = (unsigned int*)(lds + 8192);

    int blk  = blockIdx.x;
    int wt4  = blk & 3;
    int h    = (blk >> 2) & 127;
    int b    = blk >> 9;
    int w0   = wt4 * 32;
    int tid  = threadIdx.x;
    int lane = tid & 63;
    int wave = tid >> 6;
    int wave_n = wave & 1;
    int wave_m = wave >> 1;
    int px_base = wave_m * 16;
    int o_base  = wave_n * 64;
    int l15 = lane & 15, lhi = lane >> 4;

    floatx4 acc[4];
#pragma unroll
    for (int n = 0; n < 4; ++n) acc[n] = (floatx4){0.f, 0.f, 0.f, 0.f};

    const float* xtb = xt + (size_t)b * HW * CI;
    const float2* cb = coords + (((size_t)b * Hh + h) * Ww + w0) * NTAP;

    for (int t = 0; t < NTAP; ++t) {
        // ---- sampling: 8 px-tasks per wave; lane covers c = 2*lane, 2*lane+1
#pragma unroll
        for (int i = 0; i < 8; ++i) {
            int px = wave * 8 + i;
            float2 co = cb[(size_t)px * NTAP + t];
            float ix = co.x, iy = co.y;
            float fx0 = floorf(ix), fy0 = floorf(iy);
            int x0 = (int)fx0, y0 = (int)fy0;
            int x1 = x0 + 1,   y1 = y0 + 1;
            float wx1 = ix - fx0, wy1 = iy - fy0;
            float wx0 = 1.f - wx1, wy0 = 1.f - wy1;
            bool vx0 = (x0 >= 0) & (x0 < Ww);
            bool vx1 = (x1 >= 0) & (x1 < Ww);
            bool vy0 = (y0 >= 0) & (y0 < Hh);
            bool vy1 = (y1 >= 0) & (y1 < Hh);
            int cx0 = min(max(x0, 0), Ww - 1), cx1 = min(max(x1, 0), Ww - 1);
            int cy0 = min(max(y0, 0), Hh - 1), cy1 = min(max(y1, 0), Hh - 1);
            float w00 = (vy0 && vx0) ? wy0 * wx0 : 0.f;
            float w01 = (vy0 && vx1) ? wy0 * wx1 : 0.f;
            float w10 = (vy1 && vx0) ? wy1 * wx0 : 0.f;
            float w11 = (vy1 && vx1) ? wy1 * wx1 : 0.f;
            const float2* r00 = (const float2*)(xtb + ((size_t)cy0 * Ww + cx0) * CI);
            const float2* r01 = (const float2*)(xtb + ((size_t)cy0 * Ww + cx1) * CI);
            const float2* r10 = (const float2*)(xtb + ((size_t)cy1 * Ww + cx0) * CI);
            const float2* r11 = (const float2*)(xtb + ((size_t)cy1 * Ww + cx1) * CI);
            float2 p00 = r00[lane], p01 = r01[lane], p10 = r10[lane], p11 = r11[lane];
            float v0 = w00 * p00.x + w01 * p01.x + w10 * p10.x + w11 * p11.x;
            float v1 = w00 * p00.y + w01 * p01.y + w10 * p10.y + w11 * p11.y;
            unsigned short h0 = bf16_rne_bits(v0);
            unsigned short h1 = bf16_rne_bits(v1);
            float l0 = v0 - bf16_bits_to_f32(h0);
            float l1 = v1 - bf16_bits_to_f32(h1);
            unsigned int hp = (unsigned int)h0 | ((unsigned int)bf16_rne_bits(v1) << 16);
            (void)h1;
            unsigned int lp = (unsigned int)bf16_rne_bits(l0) |
                              ((unsigned int)bf16_rne_bits(l1) << 16);
            int widx = (px * 64 + lane) ^ ((px & 7) << 2);   // word-XOR swizzle
            a_hi_w[widx] = hp;
            a_lo_w[widx] = lp;
        }
        __syncthreads();

        // ---- MFMA: 4 K-steps of 32 over this tap's 128 channels
        const unsigned short* wh_t = wt_hi + (size_t)t * CI;
        const unsigned short* wl_t = wt_lo + (size_t)t * CI;
#pragma unroll
        for (int ks = 0; ks < 4; ++ks) {
            int px_r  = px_base + l15;
            int abyte = (px_r * 256 + ks * 64 + lhi * 16) ^ ((px_r & 7) << 4);
            short8 a_hi = *(const short8*)(lds + abyte);
            short8 a_lo = *(const short8*)(lds + 8192 + abyte);
            short8 bh[4], bl[4];
#pragma unroll
            for (int n = 0; n < 4; ++n) {
                size_t off = (size_t)(o_base + n * 16 + l15) * KTOT + ks * 32 + lhi * 8;
                bh[n] = *(const short8*)(wh_t + off);
                bl[n] = *(const short8*)(wl_t + off);
            }
#pragma unroll
            for (int n = 0; n < 4; ++n)
                acc[n] = __builtin_amdgcn_mfma_f32_16x16x32_bf16(a_hi, bh[n], acc[n], 0, 0, 0);
#pragma unroll
            for (int n = 0; n < 4; ++n)
                acc[n] = __builtin_amdgcn_mfma_f32_16x16x32_bf16(a_hi, bl[n], acc[n], 0, 0, 0);
#pragma unroll
            for (int n = 0; n < 4; ++n)
                acc[n] = __builtin_amdgcn_mfma_f32_16x16x32_bf16(a_lo, bh[n], acc[n], 0, 0, 0);
        }
        __syncthreads();
    }

    // ---- epilogue: transpose through LDS for coalesced stores ----
    float* epi = (float*)lds;   // [128 o][33]
#pragma unroll
    for (int n = 0; n < 4; ++n) {
        int o = o_base + n * 16 + l15;
#pragma unroll
        for (int r = 0; r < 4; ++r) {
            int px = px_base + lhi * 4 + r;
            epi[o * 33 + px] = acc[n][r];
        }
    }
    __syncthreads();
    float* ob = out + ((size_t)b * CO * Hh + h) * Ww;
    for (int i = tid; i < CO * 32; i += 256) {
        int o  = i >> 5;
        int px = i & 31;
        ob[(size_t)o * HW + w0 + px] = epi[o * 33 + px] + b_main[o];
    }
}

// ---------------------------------------------------------------------------
extern "C" void kernel_launch(void* const* d_in, const int* in_sizes, int n_in,
                              void* d_out, int out_size, void* d_ws, size_t ws_size,
                              hipStream_t stream) {
    const float* x      = (const float*)d_in[0];   // [4][128][128][128]
    const float* w_off  = (const float*)d_in[1];   // [18][128][3][3]
    const float* b_off  = (const float*)d_in[2];   // [18]
    const float* w_main = (const float*)d_in[3];   // [128][128][3][3]
    const float* b_main = (const float*)d_in[4];   // [128]
    float* out = (float*)d_out;

    // workspace layout (floats): xt | coords | woff_t | wt_hi | wt_lo
    float*  ws     = (float*)d_ws;
    float*  xt     = ws;                                        // 8,388,608 f
    float2* coords = (float2*)(ws + (size_t)Bb * HW * CI);      // 589,824 f2
    float*  woff_t = ws + (size_t)Bb * HW * CI + (size_t)Bb * HW * NTAP * 2;
    unsigned short* wt_hi = (unsigned short*)(woff_t + NOFF * 9 * CI);
    unsigned short* wt_lo = wt_hi + (size_t)CO * KTOT;

    k_transpose<<<dim3(HW / 32, CI / 32, Bb), dim3(32, 8), 0, stream>>>(x, xt);
    k_weights<<<576, 256, 0, stream>>>(w_off, w_main, woff_t, wt_hi, wt_lo);
    k_offsets<<<Bb * Hh * (Ww / 16), 256, 0, stream>>>(xt, woff_t, b_off, coords);
    k_main<<<Bb * Hh * (Ww / 32), 256, 0, stream>>>(xt, coords, wt_hi, wt_lo, b_main, out);
}

// Round 6
// 548.359 us; speedup vs baseline: 2.2719x; 1.1407x over previous
//
#include <hip/hip_runtime.h>
#include <cstddef>

// Problem constants (match reference)
#define Bb   4
#define CI   128
#define CO   128
#define Hh   128
#define Ww   128
#define HW   (Hh*Ww)
#define NOFF 18      // 2*K*K
#define NTAP 9       // K*K
#define KTOT (NTAP*CI)   // 1152

typedef short short8 __attribute__((ext_vector_type(8)));
typedef float floatx4 __attribute__((ext_vector_type(4)));

// bf16 RNE split helpers (no NaN/inf in this data)
__device__ inline unsigned short bf16_rne_bits(float f) {
    unsigned u = __float_as_uint(f);
    unsigned r = u + 0x7FFFu + ((u >> 16) & 1u);
    return (unsigned short)(r >> 16);
}
__device__ inline float bf16_bits_to_f32(unsigned short h) {
    return __uint_as_float((unsigned)h << 16);
}

// ---------------------------------------------------------------------------
// K0: transpose x NCHW -> NHWC (per batch: C x HW matrix -> HW x C)
// ---------------------------------------------------------------------------
__global__ __launch_bounds__(256) void k_transpose(const float* __restrict__ x,
                                                   float* __restrict__ xt) {
    __shared__ float tile[32][33];
    int b  = blockIdx.z;
    int c0 = blockIdx.y * 32;
    int p0 = blockIdx.x * 32;      // hw offset
    int tx = threadIdx.x;          // 0..31
    int ty = threadIdx.y;          // 0..7
    const float* xb  = x  + (size_t)b * CI * HW;
    float*       xtb = xt + (size_t)b * HW * CI;
#pragma unroll
    for (int i = 0; i < 4; ++i) {
        int c = c0 + ty + 8 * i;
        tile[ty + 8 * i][tx] = xb[(size_t)c * HW + p0 + tx];
    }
    __syncthreads();
#pragma unroll
    for (int i = 0; i < 4; ++i) {
        int p = p0 + ty + 8 * i;
        xtb[(size_t)p * CI + c0 + tx] = tile[tx][ty + 8 * i];
    }
}

// ---------------------------------------------------------------------------
// K0b: weight layout transforms
//  woff_t[((oc*3+ky)*3+kx)*128 + c] = w_off[(oc*128+c)*9 + ky*3+kx]   (fp32)
//  wfrag_hi/lo: MFMA-fragment-linear bf16 split of w_main.
//    i = ((t*4+ks)*8 + g)*512 + l*8 + j  (t=tap, ks=K-step, g=o-group, l=lane)
//    value = w_main[o = g*16+(l&15)][c = ks*32+(l>>4)*8+j][tap t]
//  -> a wave's B fragment for (t,ks,o-group) is ONE contiguous 1KB chunk.
// ---------------------------------------------------------------------------
__global__ __launch_bounds__(256) void k_weights(const float* __restrict__ w_off,
                                                 const float* __restrict__ w_main,
                                                 float* __restrict__ woff_t,
                                                 unsigned short* __restrict__ wfrag_hi,
                                                 unsigned short* __restrict__ wfrag_lo) {
    int idx = blockIdx.x * 256 + threadIdx.x;
    int stride = gridDim.x * 256;
    for (int i = idx; i < NOFF * 9 * CI; i += stride) {
        int c  = i & 127;
        int kk = (i >> 7) % 9;
        int oc = i / (9 * CI);
        woff_t[i] = w_off[(oc * CI + c) * 9 + kk];
    }
    for (int i = idx; i < CO * KTOT; i += stride) {
        int j  = i & 7;
        int l  = (i >> 3) & 63;
        int g  = (i >> 9) & 7;
        int ks = (i >> 12) & 3;
        int t  = i >> 14;                       // 0..8
        int o  = g * 16 + (l & 15);
        int c  = ks * 32 + (l >> 4) * 8 + j;    // channel within tap
        float f = w_main[(o * CI + c) * 9 + t];
        unsigned short hb = bf16_rne_bits(f);
        float lo = f - bf16_bits_to_f32(hb);
        wfrag_hi[i] = hb;
        wfrag_lo[i] = bf16_rne_bits(lo);
    }
}

// ---------------------------------------------------------------------------
// K1: offset conv (128->18, 3x3, pad 1) + per-pixel cumsum + sample coords.
// One block = 16-pixel row segment (LDS ~29.7KB -> 5 blocks/CU).
// Task map: oc = oidx>>4 (wave-broadcast weight rows), px = oidx&15.
// ---------------------------------------------------------------------------
#define PSTR 132
__global__ __launch_bounds__(256) void k_offsets(const float* __restrict__ xt,
                                                 const float* __restrict__ woff_t,
                                                 const float* __restrict__ b_off,
                                                 float2* __restrict__ coords) {
    __shared__ float patch[3 * 18 * PSTR];   // 28,512 B
    __shared__ float raw[16][19];            //  1,216 B
    int blk = blockIdx.x;
    int wt  = blk & 7;
    int h   = (blk >> 3) & 127;
    int b   = blk >> 10;
    int w0  = wt * 16;
    int tid = threadIdx.x;

    for (int i = tid; i < 3 * 18 * CI; i += 256) {
        int c   = i & 127;
        int col = (i >> 7) % 18;
        int r   = i / (18 * CI);
        int gy  = h - 1 + r;
        int gx  = w0 - 1 + col;
        float v = 0.f;
        if (gy >= 0 && gy < Hh && gx >= 0 && gx < Ww)
            v = xt[(((size_t)b * Hh + gy) * Ww + gx) * CI + c];
        patch[(r * 18 + col) * PSTR + c] = v;
    }
    __syncthreads();

    for (int oidx = tid; oidx < 16 * NOFF; oidx += 256) {
        int px = oidx & 15;
        int oc = oidx >> 4;
        float acc0 = b_off[oc], acc1 = 0.f;
#pragma unroll
        for (int ky = 0; ky < 3; ++ky) {
#pragma unroll
            for (int kx = 0; kx < 3; ++kx) {
                const float* pp = &patch[(ky * 18 + px + kx) * PSTR];
                const float* wp = &woff_t[((oc * 3 + ky) * 3 + kx) * CI];
#pragma unroll 4
                for (int c = 0; c < CI; c += 8) {
                    float4 p0 = *(const float4*)(pp + c);
                    float4 w0v = *(const float4*)(wp + c);
                    float4 p1 = *(const float4*)(pp + c + 4);
                    float4 w1v = *(const float4*)(wp + c + 4);
                    acc0 += (p0.x * w0v.x + p0.y * w0v.y)
                          + (p0.z * w0v.z + p0.w * w0v.w);
                    acc1 += (p1.x * w1v.x + p1.y * w1v.y)
                          + (p1.z * w1v.z + p1.w * w1v.w);
                }
            }
        }
        raw[px][oc] = acc0 + acc1;
    }
    __syncthreads();

    for (int i = tid; i < 16 * NTAP; i += 256) {
        int px = i / NTAP;
        int t  = i % NTAP;
        int ki = t / 3, kj = t % 3;
        float offx = 0.f, offy = 0.f;
        for (int q = 0; q <= ki; ++q) offx += raw[px][q * 6 + kj * 2 + 0];
        for (int q = 0; q <= kj; ++q) offy += raw[px][ki * 6 + q * 2 + 1];
        int wg = w0 + px;
        float xg = -1.0f + 2.0f * (float)wg / 127.0f;
        float yg = -1.0f + 2.0f * (float)h  / 127.0f;
        float gx = xg + offx;
        float gy = yg + offy;
        float ix = ((gx + 1.0f) * (float)Ww - 1.0f) * 0.5f;
        float iy = ((gy + 1.0f) * (float)Hh - 1.0f) * 0.5f;
        coords[(((size_t)b * Hh + h) * Ww + wg) * NTAP + t] = make_float2(ix, iy);
    }
}

// ---------------------------------------------------------------------------
// K2: fused bilinear sampling + split-bf16 MFMA main conv + bias.
// Block = 32 px x 128 o, 4 waves (2m x 2n). Per tap: sample -> LDS bf16
// hi/lo tiles, then ks-loop software-pipelined: B(ks+1) coalesced 1KB
// loads issued during ks's 12 MFMAs. launch_bounds(256,4): VGPR cap 128,
// 4 blocks/CU target.
// A frag: row=lane&15, k=(lane>>4)*8+j. C/D: col=lane&15, row=(lane>>4)*4+r.
// ---------------------------------------------------------------------------
__global__ __launch_bounds__(256, 4) void k_main(const float* __restrict__ xt,
                                              const float2* __restrict__ coords,
                                              const unsigned short* __restrict__ wfrag_hi,
                                              const unsigned short* __restrict__ wfrag_lo,
                                              const float* __restrict__ b_main,
                                              float* __restrict__ out) {
    // A_hi words [0,8K), A_lo [8K,16K); epilogue reuses as f32 [128][33]
    __shared__ __align__(16) char lds[17024];
    unsigned int* a_hi_w = (unsigned int*)lds;
    unsigned int* a_lo_w = (unsigned int*)(lds + 8192);

    int blk  = blockIdx.x;
    int wt4  = blk & 3;
    int h    = (blk >> 2) & 127;
    int b    = blk >> 9;
    int w0   = wt4 * 32;
    int tid  = threadIdx.x;
    int lane = tid & 63;
    int wave = tid >> 6;
    int wave_n = wave & 1;
    int wave_m = wave >> 1;
    int px_base = wave_m * 16;
    int o_base  = wave_n * 64;
    int l15 = lane & 15, lhi = lane >> 4;

    floatx4 acc[4];
#pragma unroll
    for (int n = 0; n < 4; ++n) acc[n] = (floatx4){0.f, 0.f, 0.f, 0.f};

    const float* xtb = xt + (size_t)b * HW * CI;
    const float2* cb = coords + (((size_t)b * Hh + h) * Ww + w0) * NTAP;
    const short8* whb = (const short8*)wfrag_hi;   // element = 8 shorts
    const short8* wlb = (const short8*)wfrag_lo;

    for (int t = 0; t < NTAP; ++t) {
        // ---- sampling: 8 px-tasks per wave; lane covers c = 2*lane, 2*lane+1
#pragma unroll
        for (int i = 0; i < 8; ++i) {
            int px = wave * 8 + i;
            float2 co = cb[(size_t)px * NTAP + t];
            float ix = co.x, iy = co.y;
            float fx0 = floorf(ix), fy0 = floorf(iy);
            int x0 = (int)fx0, y0 = (int)fy0;
            int x1 = x0 + 1,   y1 = y0 + 1;
            float wx1 = ix - fx0, wy1 = iy - fy0;
            float wx0 = 1.f - wx1, wy0 = 1.f - wy1;
            bool vx0 = (x0 >= 0) & (x0 < Ww);
            bool vx1 = (x1 >= 0) & (x1 < Ww);
            bool vy0 = (y0 >= 0) & (y0 < Hh);
            bool vy1 = (y1 >= 0) & (y1 < Hh);
            int cx0 = min(max(x0, 0), Ww - 1), cx1 = min(max(x1, 0), Ww - 1);
            int cy0 = min(max(y0, 0), Hh - 1), cy1 = min(max(y1, 0), Hh - 1);
            float w00 = (vy0 && vx0) ? wy0 * wx0 : 0.f;
            float w01 = (vy0 && vx1) ? wy0 * wx1 : 0.f;
            float w10 = (vy1 && vx0) ? wy1 * wx0 : 0.f;
            float w11 = (vy1 && vx1) ? wy1 * wx1 : 0.f;
            const float2* r00 = (const float2*)(xtb + ((size_t)cy0 * Ww + cx0) * CI);
            const float2* r01 = (const float2*)(xtb + ((size_t)cy0 * Ww + cx1) * CI);
            const float2* r10 = (const float2*)(xtb + ((size_t)cy1 * Ww + cx0) * CI);
            const float2* r11 = (const float2*)(xtb + ((size_t)cy1 * Ww + cx1) * CI);
            float2 p00 = r00[lane], p01 = r01[lane], p10 = r10[lane], p11 = r11[lane];
            float v0 = w00 * p00.x + w01 * p01.x + w10 * p10.x + w11 * p11.x;
            float v1 = w00 * p00.y + w01 * p01.y + w10 * p10.y + w11 * p11.y;
            unsigned short h0 = bf16_rne_bits(v0);
            unsigned short h1 = bf16_rne_bits(v1);
            float l0 = v0 - bf16_bits_to_f32(h0);
            float l1 = v1 - bf16_bits_to_f32(h1);
            unsigned int hp = (unsigned int)h0 | ((unsigned int)h1 << 16);
            unsigned int lp = (unsigned int)bf16_rne_bits(l0) |
                              ((unsigned int)bf16_rne_bits(l1) << 16);
            int widx = (px * 64 + lane) ^ ((px & 7) << 2);   // word-XOR swizzle
            a_hi_w[widx] = hp;
            a_lo_w[widx] = lp;
        }
        __syncthreads();

        // ---- MFMA: 4 K-steps of 32, software-pipelined B loads.
        // B fragment index (short8 units): ((t*4+ks)*8 + wave_n*4 + n)*64 + lane
#define BIDX(ks, n) ((size_t)(((t * 4 + (ks)) * 8) + wave_n * 4 + (n)) * 64 + lane)
        short8 bh0[4], bl0[4], bh1[4], bl1[4];
#pragma unroll
        for (int n = 0; n < 4; ++n) { bh0[n] = whb[BIDX(0, n)]; bl0[n] = wlb[BIDX(0, n)]; }
#pragma unroll
        for (int ks = 0; ks < 4; ++ks) {
            // prefetch next ks's B while this ks computes (ping-pong regs)
            if (ks < 3) {
                if ((ks & 1) == 0) {
#pragma unroll
                    for (int n = 0; n < 4; ++n) { bh1[n] = whb[BIDX(ks + 1, n)]; bl1[n] = wlb[BIDX(ks + 1, n)]; }
                } else {
#pragma unroll
                    for (int n = 0; n < 4; ++n) { bh0[n] = whb[BIDX(ks + 1, n)]; bl0[n] = wlb[BIDX(ks + 1, n)]; }
                }
            }
            int px_r  = px_base + l15;
            int abyte = (px_r * 256 + ks * 64 + lhi * 16) ^ ((px_r & 7) << 4);
            short8 a_hi = *(const short8*)(lds + abyte);
            short8 a_lo = *(const short8*)(lds + 8192 + abyte);
            if ((ks & 1) == 0) {
#pragma unroll
                for (int n = 0; n < 4; ++n)
                    acc[n] = __builtin_amdgcn_mfma_f32_16x16x32_bf16(a_hi, bh0[n], acc[n], 0, 0, 0);
#pragma unroll
                for (int n = 0; n < 4; ++n)
                    acc[n] = __builtin_amdgcn_mfma_f32_16x16x32_bf16(a_hi, bl0[n], acc[n], 0, 0, 0);
#pragma unroll
                for (int n = 0; n < 4; ++n)
                    acc[n] = __builtin_amdgcn_mfma_f32_16x16x32_bf16(a_lo, bh0[n], acc[n], 0, 0, 0);
            } else {
#pragma unroll
                for (int n = 0; n < 4; ++n)
                    acc[n] = __builtin_amdgcn_mfma_f32_16x16x32_bf16(a_hi, bh1[n], acc[n], 0, 0, 0);
#pragma unroll
                for (int n = 0; n < 4; ++n)
                    acc[n] = __builtin_amdgcn_mfma_f32_16x16x32_bf16(a_hi, bl1[n], acc[n], 0, 0, 0);
#pragma unroll
                for (int n = 0; n < 4; ++n)
                    acc[n] = __builtin_amdgcn_mfma_f32_16x16x32_bf16(a_lo, bh1[n], acc[n], 0, 0, 0);
            }
        }
#undef BIDX
        __syncthreads();
    }

    // ---- epilogue: transpose through LDS for coalesced stores ----
    float* epi = (float*)lds;   // [128 o][33]
#pragma unroll
    for (int n = 0; n < 4; ++n) {
        int o = o_base + n * 16 + l15;
#pragma unroll
        for (int r = 0; r < 4; ++r) {
            int px = px_base + lhi * 4 + r;
            epi[o * 33 + px] = acc[n][r];
        }
    }
    __syncthreads();
    float* ob = out + ((size_t)b * CO * Hh + h) * Ww;
    for (int i = tid; i < CO * 32; i += 256) {
        int o  = i >> 5;
        int px = i & 31;
        ob[(size_t)o * HW + w0 + px] = epi[o * 33 + px] + b_main[o];
    }
}

// ---------------------------------------------------------------------------
extern "C" void kernel_launch(void* const* d_in, const int* in_sizes, int n_in,
                              void* d_out, int out_size, void* d_ws, size_t ws_size,
                              hipStream_t stream) {
    const float* x      = (const float*)d_in[0];   // [4][128][128][128]
    const float* w_off  = (const float*)d_in[1];   // [18][128][3][3]
    const float* b_off  = (const float*)d_in[2];   // [18]
    const float* w_main = (const float*)d_in[3];   // [128][128][3][3]
    const float* b_main = (const float*)d_in[4];   // [128]
    float* out = (float*)d_out;

    // workspace layout (floats): xt | coords | woff_t | wfrag_hi | wfrag_lo
    float*  ws     = (float*)d_ws;
    float*  xt     = ws;                                        // 8,388,608 f
    float2* coords = (float2*)(ws + (size_t)Bb * HW * CI);      // 589,824 f2
    float*  woff_t = ws + (size_t)Bb * HW * CI + (size_t)Bb * HW * NTAP * 2;
    unsigned short* wfrag_hi = (unsigned short*)(woff_t + NOFF * 9 * CI);
    unsigned short* wfrag_lo = wfrag_hi + (size_t)CO * KTOT;

    k_transpose<<<dim3(HW / 32, CI / 32, Bb), dim3(32, 8), 0, stream>>>(x, xt);
    k_weights<<<576, 256, 0, stream>>>(w_off, w_main, woff_t, wfrag_hi, wfrag_lo);
    k_offsets<<<Bb * Hh * (Ww / 16), 256, 0, stream>>>(xt, woff_t, b_off, coords);
    k_main<<<Bb * Hh * (Ww / 32), 256, 0, stream>>>(xt, coords, wfrag_hi, wfrag_lo, b_main, out);
}

// Round 7
// 541.098 us; speedup vs baseline: 2.3024x; 1.0134x over previous
//
#include <hip/hip_runtime.h>
#include <cstddef>

// Problem constants (match reference)
#define Bb   4
#define CI   128
#define CO   128
#define Hh   128
#define Ww   128
#define HW   (Hh*Ww)
#define NOFF 18      // 2*K*K
#define NTAP 9       // K*K
#define KTOT (NTAP*CI)   // 1152

typedef short short8 __attribute__((ext_vector_type(8)));
typedef float floatx4 __attribute__((ext_vector_type(4)));

// bf16 RNE split helpers (no NaN/inf in this data)
__device__ inline unsigned short bf16_rne_bits(float f) {
    unsigned u = __float_as_uint(f);
    unsigned r = u + 0x7FFFu + ((u >> 16) & 1u);
    return (unsigned short)(r >> 16);
}
__device__ inline float bf16_bits_to_f32(unsigned short h) {
    return __uint_as_float((unsigned)h << 16);
}

// ---------------------------------------------------------------------------
// K0: transpose x NCHW -> NHWC (per batch: C x HW matrix -> HW x C)
// ---------------------------------------------------------------------------
__global__ __launch_bounds__(256) void k_transpose(const float* __restrict__ x,
                                                   float* __restrict__ xt) {
    __shared__ float tile[32][33];
    int b  = blockIdx.z;
    int c0 = blockIdx.y * 32;
    int p0 = blockIdx.x * 32;      // hw offset
    int tx = threadIdx.x;          // 0..31
    int ty = threadIdx.y;          // 0..7
    const float* xb  = x  + (size_t)b * CI * HW;
    float*       xtb = xt + (size_t)b * HW * CI;
#pragma unroll
    for (int i = 0; i < 4; ++i) {
        int c = c0 + ty + 8 * i;
        tile[ty + 8 * i][tx] = xb[(size_t)c * HW + p0 + tx];
    }
    __syncthreads();
#pragma unroll
    for (int i = 0; i < 4; ++i) {
        int p = p0 + ty + 8 * i;
        xtb[(size_t)p * CI + c0 + tx] = tile[tx][ty + 8 * i];
    }
}

// ---------------------------------------------------------------------------
// K0b: weight layout transforms
//  woff_t[((oc*3+ky)*3+kx)*128 + c] = w_off[(oc*128+c)*9 + ky*3+kx]   (fp32)
//  wfrag_hi/lo: MFMA-fragment-linear bf16 split of w_main.
//    i = ((t*4+ks)*8 + g)*512 + l*8 + j  (t=tap, ks=K-step, g=o-group, l=lane)
//    value = w_main[o = g*16+(l&15)][c = ks*32+(l>>4)*8+j][tap t]
//  -> a wave's B fragment for (t,ks,o-group) is ONE contiguous 1KB chunk.
// ---------------------------------------------------------------------------
__global__ __launch_bounds__(256) void k_weights(const float* __restrict__ w_off,
                                                 const float* __restrict__ w_main,
                                                 float* __restrict__ woff_t,
                                                 unsigned short* __restrict__ wfrag_hi,
                                                 unsigned short* __restrict__ wfrag_lo) {
    int idx = blockIdx.x * 256 + threadIdx.x;
    int stride = gridDim.x * 256;
    for (int i = idx; i < NOFF * 9 * CI; i += stride) {
        int c  = i & 127;
        int kk = (i >> 7) % 9;
        int oc = i / (9 * CI);
        woff_t[i] = w_off[(oc * CI + c) * 9 + kk];
    }
    for (int i = idx; i < CO * KTOT; i += stride) {
        int j  = i & 7;
        int l  = (i >> 3) & 63;
        int g  = (i >> 9) & 7;
        int ks = (i >> 12) & 3;
        int t  = i >> 14;                       // 0..8
        int o  = g * 16 + (l & 15);
        int c  = ks * 32 + (l >> 4) * 8 + j;    // channel within tap
        float f = w_main[(o * CI + c) * 9 + t];
        unsigned short hb = bf16_rne_bits(f);
        float lo = f - bf16_bits_to_f32(hb);
        wfrag_hi[i] = hb;
        wfrag_lo[i] = bf16_rne_bits(lo);
    }
}

// ---------------------------------------------------------------------------
// K1: offset conv (128->18, 3x3, pad 1) + per-pixel cumsum + sample coords.
// One block = 16-pixel row segment (LDS ~29.7KB -> 5 blocks/CU).
// Task map: oc = oidx>>4 (wave-broadcast weight rows), px = oidx&15.
// ---------------------------------------------------------------------------
#define PSTR 132
__global__ __launch_bounds__(256) void k_offsets(const float* __restrict__ xt,
                                                 const float* __restrict__ woff_t,
                                                 const float* __restrict__ b_off,
                                                 float2* __restrict__ coords) {
    __shared__ float patch[3 * 18 * PSTR];   // 28,512 B
    __shared__ float raw[16][19];            //  1,216 B
    int blk = blockIdx.x;
    int wt  = blk & 7;
    int h   = (blk >> 3) & 127;
    int b   = blk >> 10;
    int w0  = wt * 16;
    int tid = threadIdx.x;

    for (int i = tid; i < 3 * 18 * CI; i += 256) {
        int c   = i & 127;
        int col = (i >> 7) % 18;
        int r   = i / (18 * CI);
        int gy  = h - 1 + r;
        int gx  = w0 - 1 + col;
        float v = 0.f;
        if (gy >= 0 && gy < Hh && gx >= 0 && gx < Ww)
            v = xt[(((size_t)b * Hh + gy) * Ww + gx) * CI + c];
        patch[(r * 18 + col) * PSTR + c] = v;
    }
    __syncthreads();

    for (int oidx = tid; oidx < 16 * NOFF; oidx += 256) {
        int px = oidx & 15;
        int oc = oidx >> 4;
        float acc0 = b_off[oc], acc1 = 0.f;
#pragma unroll
        for (int ky = 0; ky < 3; ++ky) {
#pragma unroll
            for (int kx = 0; kx < 3; ++kx) {
                const float* pp = &patch[(ky * 18 + px + kx) * PSTR];
                const float* wp = &woff_t[((oc * 3 + ky) * 3 + kx) * CI];
#pragma unroll 4
                for (int c = 0; c < CI; c += 8) {
                    float4 p0 = *(const float4*)(pp + c);
                    float4 w0v = *(const float4*)(wp + c);
                    float4 p1 = *(const float4*)(pp + c + 4);
                    float4 w1v = *(const float4*)(wp + c + 4);
                    acc0 += (p0.x * w0v.x + p0.y * w0v.y)
                          + (p0.z * w0v.z + p0.w * w0v.w);
                    acc1 += (p1.x * w1v.x + p1.y * w1v.y)
                          + (p1.z * w1v.z + p1.w * w1v.w);
                }
            }
        }
        raw[px][oc] = acc0 + acc1;
    }
    __syncthreads();

    for (int i = tid; i < 16 * NTAP; i += 256) {
        int px = i / NTAP;
        int t  = i % NTAP;
        int ki = t / 3, kj = t % 3;
        float offx = 0.f, offy = 0.f;
        for (int q = 0; q <= ki; ++q) offx += raw[px][q * 6 + kj * 2 + 0];
        for (int q = 0; q <= kj; ++q) offy += raw[px][ki * 6 + q * 2 + 1];
        int wg = w0 + px;
        float xg = -1.0f + 2.0f * (float)wg / 127.0f;
        float yg = -1.0f + 2.0f * (float)h  / 127.0f;
        float gx = xg + offx;
        float gy = yg + offy;
        float ix = ((gx + 1.0f) * (float)Ww - 1.0f) * 0.5f;
        float iy = ((gy + 1.0f) * (float)Hh - 1.0f) * 0.5f;
        coords[(((size_t)b * Hh + h) * Ww + wg) * NTAP + t] = make_float2(ix, iy);
    }
}

// ---------------------------------------------------------------------------
// K2: fused bilinear sampling + split-bf16 MFMA main conv + bias.
// Block = 32 px x 128 o, 4 waves (2m x 2n). Per tap: sample -> LDS bf16
// hi/lo tiles, then ks-loop software-pipelined B loads.
// XCD swizzle (T1): hw blocks round-robin across 8 XCDs; remap so each XCD
// owns 256 consecutive logical blocks = 64 contiguous image rows -> per-XCD
// sampling working set ~4.3MB = L2-resident (was 8x spread, 525MB FETCH).
// ---------------------------------------------------------------------------
__global__ __launch_bounds__(256, 4) void k_main(const float* __restrict__ xt,
                                              const float2* __restrict__ coords,
                                              const unsigned short* __restrict__ wfrag_hi,
                                              const unsigned short* __restrict__ wfrag_lo,
                                              const float* __restrict__ b_main,
                                              float* __restrict__ out) {
    // A_hi words [0,8K), A_lo [8K,16K); epilogue reuses as f32 [128][33]
    __shared__ __align__(16) char lds[17024];
    unsigned int* a_hi_w = (unsigned int*)lds;
    unsigned int* a_lo_w = (unsigned int*)(lds + 8192);

    int blk  = blockIdx.x;
    blk = (blk & 7) * 256 + (blk >> 3);   // XCD-contiguous remap (2048 % 8 == 0)
    int wt4  = blk & 3;
    int h    = (blk >> 2) & 127;
    int b    = blk >> 9;
    int w0   = wt4 * 32;
    int tid  = threadIdx.x;
    int lane = tid & 63;
    int wave = tid >> 6;
    int wave_n = wave & 1;
    int wave_m = wave >> 1;
    int px_base = wave_m * 16;
    int o_base  = wave_n * 64;
    int l15 = lane & 15, lhi = lane >> 4;

    floatx4 acc[4];
#pragma unroll
    for (int n = 0; n < 4; ++n) acc[n] = (floatx4){0.f, 0.f, 0.f, 0.f};

    const float* xtb = xt + (size_t)b * HW * CI;
    const float2* cb = coords + (((size_t)b * Hh + h) * Ww + w0) * NTAP;
    const short8* whb = (const short8*)wfrag_hi;   // element = 8 shorts
    const short8* wlb = (const short8*)wfrag_lo;

    for (int t = 0; t < NTAP; ++t) {
        // ---- sampling: 8 px-tasks per wave; lane covers c = 2*lane, 2*lane+1
#pragma unroll
        for (int i = 0; i < 8; ++i) {
            int px = wave * 8 + i;
            float2 co = cb[(size_t)px * NTAP + t];
            float ix = co.x, iy = co.y;
            float fx0 = floorf(ix), fy0 = floorf(iy);
            int x0 = (int)fx0, y0 = (int)fy0;
            int x1 = x0 + 1,   y1 = y0 + 1;
            float wx1 = ix - fx0, wy1 = iy - fy0;
            float wx0 = 1.f - wx1, wy0 = 1.f - wy1;
            bool vx0 = (x0 >= 0) & (x0 < Ww);
            bool vx1 = (x1 >= 0) & (x1 < Ww);
            bool vy0 = (y0 >= 0) & (y0 < Hh);
            bool vy1 = (y1 >= 0) & (y1 < Hh);
            int cx0 = min(max(x0, 0), Ww - 1), cx1 = min(max(x1, 0), Ww - 1);
            int cy0 = min(max(y0, 0), Hh - 1), cy1 = min(max(y1, 0), Hh - 1);
            float w00 = (vy0 && vx0) ? wy0 * wx0 : 0.f;
            float w01 = (vy0 && vx1) ? wy0 * wx1 : 0.f;
            float w10 = (vy1 && vx0) ? wy1 * wx0 : 0.f;
            float w11 = (vy1 && vx1) ? wy1 * wx1 : 0.f;
            const float2* r00 = (const float2*)(xtb + ((size_t)cy0 * Ww + cx0) * CI);
            const float2* r01 = (const float2*)(xtb + ((size_t)cy0 * Ww + cx1) * CI);
            const float2* r10 = (const float2*)(xtb + ((size_t)cy1 * Ww + cx0) * CI);
            const float2* r11 = (const float2*)(xtb + ((size_t)cy1 * Ww + cx1) * CI);
            float2 p00 = r00[lane], p01 = r01[lane], p10 = r10[lane], p11 = r11[lane];
            float v0 = w00 * p00.x + w01 * p01.x + w10 * p10.x + w11 * p11.x;
            float v1 = w00 * p00.y + w01 * p01.y + w10 * p10.y + w11 * p11.y;
            unsigned short h0 = bf16_rne_bits(v0);
            unsigned short h1 = bf16_rne_bits(v1);
            float l0 = v0 - bf16_bits_to_f32(h0);
            float l1 = v1 - bf16_bits_to_f32(h1);
            unsigned int hp = (unsigned int)h0 | ((unsigned int)h1 << 16);
            unsigned int lp = (unsigned int)bf16_rne_bits(l0) |
                              ((unsigned int)bf16_rne_bits(l1) << 16);
            int widx = (px * 64 + lane) ^ ((px & 7) << 2);   // word-XOR swizzle
            a_hi_w[widx] = hp;
            a_lo_w[widx] = lp;
        }
        __syncthreads();

        // ---- MFMA: 4 K-steps of 32, software-pipelined B loads.
        // B fragment index (short8 units): ((t*4+ks)*8 + wave_n*4 + n)*64 + lane
#define BIDX(ks, n) ((size_t)(((t * 4 + (ks)) * 8) + wave_n * 4 + (n)) * 64 + lane)
        short8 bh0[4], bl0[4], bh1[4], bl1[4];
#pragma unroll
        for (int n = 0; n < 4; ++n) { bh0[n] = whb[BIDX(0, n)]; bl0[n] = wlb[BIDX(0, n)]; }
#pragma unroll
        for (int ks = 0; ks < 4; ++ks) {
            // prefetch next ks's B while this ks computes (ping-pong regs)
            if (ks < 3) {
                if ((ks & 1) == 0) {
#pragma unroll
                    for (int n = 0; n < 4; ++n) { bh1[n] = whb[BIDX(ks + 1, n)]; bl1[n] = wlb[BIDX(ks + 1, n)]; }
                } else {
#pragma unroll
                    for (int n = 0; n < 4; ++n) { bh0[n] = whb[BIDX(ks + 1, n)]; bl0[n] = wlb[BIDX(ks + 1, n)]; }
                }
            }
            int px_r  = px_base + l15;
            int abyte = (px_r * 256 + ks * 64 + lhi * 16) ^ ((px_r & 7) << 4);
            short8 a_hi = *(const short8*)(lds + abyte);
            short8 a_lo = *(const short8*)(lds + 8192 + abyte);
            if ((ks & 1) == 0) {
#pragma unroll
                for (int n = 0; n < 4; ++n)
                    acc[n] = __builtin_amdgcn_mfma_f32_16x16x32_bf16(a_hi, bh0[n], acc[n], 0, 0, 0);
#pragma unroll
                for (int n = 0; n < 4; ++n)
                    acc[n] = __builtin_amdgcn_mfma_f32_16x16x32_bf16(a_hi, bl0[n], acc[n], 0, 0, 0);
#pragma unroll
                for (int n = 0; n < 4; ++n)
                    acc[n] = __builtin_amdgcn_mfma_f32_16x16x32_bf16(a_lo, bh0[n], acc[n], 0, 0, 0);
            } else {
#pragma unroll
                for (int n = 0; n < 4; ++n)
                    acc[n] = __builtin_amdgcn_mfma_f32_16x16x32_bf16(a_hi, bh1[n], acc[n], 0, 0, 0);
#pragma unroll
                for (int n = 0; n < 4; ++n)
                    acc[n] = __builtin_amdgcn_mfma_f32_16x16x32_bf16(a_hi, bl1[n], acc[n], 0, 0, 0);
#pragma unroll
                for (int n = 0; n < 4; ++n)
                    acc[n] = __builtin_amdgcn_mfma_f32_16x16x32_bf16(a_lo, bh1[n], acc[n], 0, 0, 0);
            }
        }
#undef BIDX
        __syncthreads();
    }

    // ---- epilogue: transpose through LDS for coalesced stores ----
    float* epi = (float*)lds;   // [128 o][33]
#pragma unroll
    for (int n = 0; n < 4; ++n) {
        int o = o_base + n * 16 + l15;
#pragma unroll
        for (int r = 0; r < 4; ++r) {
            int px = px_base + lhi * 4 + r;
            epi[o * 33 + px] = acc[n][r];
        }
    }
    __syncthreads();
    float* ob = out + ((size_t)b * CO * Hh + h) * Ww;
    for (int i = tid; i < CO * 32; i += 256) {
        int o  = i >> 5;
        int px = i & 31;
        ob[(size_t)o * HW + w0 + px] = epi[o * 33 + px] + b_main[o];
    }
}

// ---------------------------------------------------------------------------
extern "C" void kernel_launch(void* const* d_in, const int* in_sizes, int n_in,
                              void* d_out, int out_size, void* d_ws, size_t ws_size,
                              hipStream_t stream) {
    const float* x      = (const float*)d_in[0];   // [4][128][128][128]
    const float* w_off  = (const float*)d_in[1];   // [18][128][3][3]
    const float* b_off  = (const float*)d_in[2];   // [18]
    const float* w_main = (const float*)d_in[3];   // [128][128][3][3]
    const float* b_main = (const float*)d_in[4];   // [128]
    float* out = (float*)d_out;

    // workspace layout (floats): xt | coords | woff_t | wfrag_hi | wfrag_lo
    float*  ws     = (float*)d_ws;
    float*  xt     = ws;                                        // 8,388,608 f
    float2* coords = (float2*)(ws + (size_t)Bb * HW * CI);      // 589,824 f2
    float*  woff_t = ws + (size_t)Bb * HW * CI + (size_t)Bb * HW * NTAP * 2;
    unsigned short* wfrag_hi = (unsigned short*)(woff_t + NOFF * 9 * CI);
    unsigned short* wfrag_lo = wfrag_hi + (size_t)CO * KTOT;

    k_transpose<<<dim3(HW / 32, CI / 32, Bb), dim3(32, 8), 0, stream>>>(x, xt);
    k_weights<<<576, 256, 0, stream>>>(w_off, w_main, woff_t, wfrag_hi, wfrag_lo);
    k_offsets<<<Bb * Hh * (Ww / 16), 256, 0, stream>>>(xt, woff_t, b_off, coords);
    k_main<<<Bb * Hh * (Ww / 32), 256, 0, stream>>>(xt, coords, wfrag_hi, wfrag_lo, b_main, out);
}

// Round 8
// 478.011 us; speedup vs baseline: 2.6063x; 1.1320x over previous
//
#include <hip/hip_runtime.h>
#include <cstddef>

// Problem constants (match reference)
#define Bb   4
#define CI   128
#define CO   128
#define Hh   128
#define Ww   128
#define HW   (Hh*Ww)
#define NOFF 18      // 2*K*K
#define NTAP 9       // K*K
#define KTOT (NTAP*CI)   // 1152
#define NSTEP 36     // K-steps of 32: NTAP*4

typedef short short8 __attribute__((ext_vector_type(8)));
typedef float floatx4 __attribute__((ext_vector_type(4)));

// bf16 RNE split helpers (no NaN/inf in this data)
__device__ inline unsigned short bf16_rne_bits(float f) {
    unsigned u = __float_as_uint(f);
    unsigned r = u + 0x7FFFu + ((u >> 16) & 1u);
    return (unsigned short)(r >> 16);
}
__device__ inline float bf16_bits_to_f32(unsigned short h) {
    return __uint_as_float((unsigned)h << 16);
}

// ---------------------------------------------------------------------------
// K0: transpose x NCHW -> NHWC
// ---------------------------------------------------------------------------
__global__ __launch_bounds__(256) void k_transpose(const float* __restrict__ x,
                                                   float* __restrict__ xt) {
    __shared__ float tile[32][33];
    int b  = blockIdx.z;
    int c0 = blockIdx.y * 32;
    int p0 = blockIdx.x * 32;
    int tx = threadIdx.x;
    int ty = threadIdx.y;
    const float* xb  = x  + (size_t)b * CI * HW;
    float*       xtb = xt + (size_t)b * HW * CI;
#pragma unroll
    for (int i = 0; i < 4; ++i) {
        int c = c0 + ty + 8 * i;
        tile[ty + 8 * i][tx] = xb[(size_t)c * HW + p0 + tx];
    }
    __syncthreads();
#pragma unroll
    for (int i = 0; i < 4; ++i) {
        int p = p0 + ty + 8 * i;
        xtb[(size_t)p * CI + c0 + tx] = tile[tx][ty + 8 * i];
    }
}

// ---------------------------------------------------------------------------
// K0b: weight layout transforms (woff_t fp32; wfrag_hi/lo fragment-linear)
//  wfrag: i = ((t*4+ks)*8 + g)*512 + l*8 + j ;
//  value = w_main[o = g*16+(l&15)][c = ks*32+(l>>4)*8+j][tap t]
// ---------------------------------------------------------------------------
__global__ __launch_bounds__(256) void k_weights(const float* __restrict__ w_off,
                                                 const float* __restrict__ w_main,
                                                 float* __restrict__ woff_t,
                                                 unsigned short* __restrict__ wfrag_hi,
                                                 unsigned short* __restrict__ wfrag_lo) {
    int idx = blockIdx.x * 256 + threadIdx.x;
    int stride = gridDim.x * 256;
    for (int i = idx; i < NOFF * 9 * CI; i += stride) {
        int c  = i & 127;
        int kk = (i >> 7) % 9;
        int oc = i / (9 * CI);
        woff_t[i] = w_off[(oc * CI + c) * 9 + kk];
    }
    for (int i = idx; i < CO * KTOT; i += stride) {
        int j  = i & 7;
        int l  = (i >> 3) & 63;
        int g  = (i >> 9) & 7;
        int ks = (i >> 12) & 3;
        int t  = i >> 14;
        int o  = g * 16 + (l & 15);
        int c  = ks * 32 + (l >> 4) * 8 + j;
        float f = w_main[(o * CI + c) * 9 + t];
        unsigned short hb = bf16_rne_bits(f);
        float lo = f - bf16_bits_to_f32(hb);
        wfrag_hi[i] = hb;
        wfrag_lo[i] = bf16_rne_bits(lo);
    }
}

// ---------------------------------------------------------------------------
// K1: offset conv + cumsum + sample coords (unchanged from R5)
// ---------------------------------------------------------------------------
#define PSTR 132
__global__ __launch_bounds__(256) void k_offsets(const float* __restrict__ xt,
                                                 const float* __restrict__ woff_t,
                                                 const float* __restrict__ b_off,
                                                 float2* __restrict__ coords) {
    __shared__ float patch[3 * 18 * PSTR];
    __shared__ float raw[16][19];
    int blk = blockIdx.x;
    int wt  = blk & 7;
    int h   = (blk >> 3) & 127;
    int b   = blk >> 10;
    int w0  = wt * 16;
    int tid = threadIdx.x;

    for (int i = tid; i < 3 * 18 * CI; i += 256) {
        int c   = i & 127;
        int col = (i >> 7) % 18;
        int r   = i / (18 * CI);
        int gy  = h - 1 + r;
        int gx  = w0 - 1 + col;
        float v = 0.f;
        if (gy >= 0 && gy < Hh && gx >= 0 && gx < Ww)
            v = xt[(((size_t)b * Hh + gy) * Ww + gx) * CI + c];
        patch[(r * 18 + col) * PSTR + c] = v;
    }
    __syncthreads();

    for (int oidx = tid; oidx < 16 * NOFF; oidx += 256) {
        int px = oidx & 15;
        int oc = oidx >> 4;
        float acc0 = b_off[oc], acc1 = 0.f;
#pragma unroll
        for (int ky = 0; ky < 3; ++ky) {
#pragma unroll
            for (int kx = 0; kx < 3; ++kx) {
                const float* pp = &patch[(ky * 18 + px + kx) * PSTR];
                const float* wp = &woff_t[((oc * 3 + ky) * 3 + kx) * CI];
#pragma unroll 4
                for (int c = 0; c < CI; c += 8) {
                    float4 p0 = *(const float4*)(pp + c);
                    float4 w0v = *(const float4*)(wp + c);
                    float4 p1 = *(const float4*)(pp + c + 4);
                    float4 w1v = *(const float4*)(wp + c + 4);
                    acc0 += (p0.x * w0v.x + p0.y * w0v.y)
                          + (p0.z * w0v.z + p0.w * w0v.w);
                    acc1 += (p1.x * w1v.x + p1.y * w1v.y)
                          + (p1.z * w1v.z + p1.w * w1v.w);
                }
            }
        }
        raw[px][oc] = acc0 + acc1;
    }
    __syncthreads();

    for (int i = tid; i < 16 * NTAP; i += 256) {
        int px = i / NTAP;
        int t  = i % NTAP;
        int ki = t / 3, kj = t % 3;
        float offx = 0.f, offy = 0.f;
        for (int q = 0; q <= ki; ++q) offx += raw[px][q * 6 + kj * 2 + 0];
        for (int q = 0; q <= kj; ++q) offy += raw[px][ki * 6 + q * 2 + 1];
        int wg = w0 + px;
        float xg = -1.0f + 2.0f * (float)wg / 127.0f;
        float yg = -1.0f + 2.0f * (float)h  / 127.0f;
        float gx = xg + offx;
        float gy = yg + offy;
        float ix = ((gx + 1.0f) * (float)Ww - 1.0f) * 0.5f;
        float iy = ((gy + 1.0f) * (float)Hh - 1.0f) * 0.5f;
        coords[(((size_t)b * Hh + h) * Ww + wg) * NTAP + t] = make_float2(ix, iy);
    }
}

// ---------------------------------------------------------------------------
// K2a: k_sample — bilinear sample + bf16 hi/lo split, written FRAGMENT-LINEAR.
// Wave = 16 px (one P-tile) x 1 tap. lane=(r,q): r=px, q=c-octet.
// Lane reads its own 8-channel window from the 4 neighbor rows (gather at
// 32B/lane granularity), packs short8 hi/lo, stores 16B/lane -> each store
// is one contiguous 1KB wave-store. No LDS, no barriers: pure TLP.
//  afrag idx (short8 units): (Pl*36 + tap*4 + ks)*64 + lane
// ---------------------------------------------------------------------------
__global__ __launch_bounds__(256) void k_sample(const float* __restrict__ xt,
                                                const float2* __restrict__ coords,
                                                unsigned short* __restrict__ afh,
                                                unsigned short* __restrict__ afl,
                                                int q0) {
    int nb = gridDim.x;
    int blkid = blockIdx.x;
    int cpx = nb >> 3;
    blkid = (blkid & 7) * cpx + (blkid >> 3);   // XCD-contiguous remap (nb%8==0)
    int task = blkid * 4 + (threadIdx.x >> 6);
    int lane = threadIdx.x & 63;
    int Pl   = task / 9;
    int tap  = task - Pl * 9;
    int r = lane & 15, q = lane >> 4;
    int p = q0 + Pl * 16 + r;          // global pixel
    int b = p >> 14;

    float2 co = coords[(size_t)p * NTAP + tap];
    float ix = co.x, iy = co.y;
    float fx0 = floorf(ix), fy0 = floorf(iy);
    int x0 = (int)fx0, y0 = (int)fy0;
    int x1 = x0 + 1,   y1 = y0 + 1;
    float wx1 = ix - fx0, wy1 = iy - fy0;
    float wx0 = 1.f - wx1, wy0 = 1.f - wy1;
    bool vx0 = (x0 >= 0) & (x0 < Ww);
    bool vx1 = (x1 >= 0) & (x1 < Ww);
    bool vy0 = (y0 >= 0) & (y0 < Hh);
    bool vy1 = (y1 >= 0) & (y1 < Hh);
    int cx0 = min(max(x0, 0), Ww - 1), cx1 = min(max(x1, 0), Ww - 1);
    int cy0 = min(max(y0, 0), Hh - 1), cy1 = min(max(y1, 0), Hh - 1);
    float w00 = (vy0 && vx0) ? wy0 * wx0 : 0.f;
    float w01 = (vy0 && vx1) ? wy0 * wx1 : 0.f;
    float w10 = (vy1 && vx0) ? wy1 * wx0 : 0.f;
    float w11 = (vy1 && vx1) ? wy1 * wx1 : 0.f;

    const float* xb  = xt + (size_t)b * HW * CI + q * 8;
    const float* r00 = xb + ((size_t)cy0 * Ww + cx0) * CI;
    const float* r01 = xb + ((size_t)cy0 * Ww + cx1) * CI;
    const float* r10 = xb + ((size_t)cy1 * Ww + cx0) * CI;
    const float* r11 = xb + ((size_t)cy1 * Ww + cx1) * CI;
    size_t obase = ((size_t)(Pl * 36 + tap * 4) * 64 + lane) * 8;

#pragma unroll
    for (int ks = 0; ks < 4; ++ks) {
        int c = ks * 32;
        float4 a0 = *(const float4*)(r00 + c), a1 = *(const float4*)(r00 + c + 4);
        float4 b0 = *(const float4*)(r01 + c), b1 = *(const float4*)(r01 + c + 4);
        float4 c0 = *(const float4*)(r10 + c), c1 = *(const float4*)(r10 + c + 4);
        float4 d0 = *(const float4*)(r11 + c), d1 = *(const float4*)(r11 + c + 4);
        float v[8];
        v[0] = w00 * a0.x + w01 * b0.x + w10 * c0.x + w11 * d0.x;
        v[1] = w00 * a0.y + w01 * b0.y + w10 * c0.y + w11 * d0.y;
        v[2] = w00 * a0.z + w01 * b0.z + w10 * c0.z + w11 * d0.z;
        v[3] = w00 * a0.w + w01 * b0.w + w10 * c0.w + w11 * d0.w;
        v[4] = w00 * a1.x + w01 * b1.x + w10 * c1.x + w11 * d1.x;
        v[5] = w00 * a1.y + w01 * b1.y + w10 * c1.y + w11 * d1.y;
        v[6] = w00 * a1.z + w01 * b1.z + w10 * c1.z + w11 * d1.z;
        v[7] = w00 * a1.w + w01 * b1.w + w10 * c1.w + w11 * d1.w;
        short8 hi, lo;
#pragma unroll
        for (int j = 0; j < 8; ++j) {
            unsigned short hb = bf16_rne_bits(v[j]);
            hi[j] = (short)hb;
            lo[j] = (short)bf16_rne_bits(v[j] - bf16_bits_to_f32(hb));
        }
        *(short8*)(afh + obase + (size_t)ks * 512) = hi;
        *(short8*)(afl + obase + (size_t)ks * 512) = lo;
    }
}

// ---------------------------------------------------------------------------
// K2b: k_gemm — register GEMM on pre-sampled fragments. Block = 32px x 128o,
// 4 waves (2m x 2n), wave = 16px x 64o. 36 K-steps, ping-pong prefetch.
// All loads are contiguous 1KB wave-loads; no LDS/barriers in main loop.
// ---------------------------------------------------------------------------
__global__ __launch_bounds__(256, 2) void k_gemm(const unsigned short* __restrict__ afh,
                                                 const unsigned short* __restrict__ afl,
                                                 const unsigned short* __restrict__ wfh,
                                                 const unsigned short* __restrict__ wfl,
                                                 const float* __restrict__ b_main,
                                                 float* __restrict__ out, int q0) {
    __shared__ __align__(16) float epi[CO * 33];   // 16,896 B (epilogue only)
    int nb = gridDim.x;
    int cpx = nb >> 3;
    int blk = blockIdx.x;
    blk = (blk & 7) * cpx + (blk >> 3);            // XCD remap (nb%8==0)
    int tid = threadIdx.x, lane = tid & 63, wave = tid >> 6;
    int wave_n = wave & 1, wave_m = wave >> 1;
    int l15 = lane & 15, lhi = lane >> 4;
    int P = blk * 2 + wave_m;                      // local 16-px tile

    const short8* ah = (const short8*)afh + (size_t)P * NSTEP * 64 + lane;
    const short8* al = (const short8*)afl + (size_t)P * NSTEP * 64 + lane;
    const short8* bh = (const short8*)wfh + (size_t)wave_n * 4 * 64 + lane;
    const short8* bl = (const short8*)wfl + (size_t)wave_n * 4 * 64 + lane;

    floatx4 acc[4];
#pragma unroll
    for (int n = 0; n < 4; ++n) acc[n] = (floatx4){0.f, 0.f, 0.f, 0.f};

    short8 A0h, A0l, B0h[4], B0l[4], A1h, A1l, B1h[4], B1l[4];
    A0h = ah[0]; A0l = al[0];
#pragma unroll
    for (int n = 0; n < 4; ++n) { B0h[n] = bh[(size_t)n * 64]; B0l[n] = bl[(size_t)n * 64]; }

#define DO_MFMA(Ah, Al, Bh, Bl)                                                   \
    {                                                                             \
        _Pragma("unroll")                                                         \
        for (int n = 0; n < 4; ++n)                                               \
            acc[n] = __builtin_amdgcn_mfma_f32_16x16x32_bf16(Ah, Bh[n], acc[n], 0, 0, 0); \
        _Pragma("unroll")                                                         \
        for (int n = 0; n < 4; ++n)                                               \
            acc[n] = __builtin_amdgcn_mfma_f32_16x16x32_bf16(Ah, Bl[n], acc[n], 0, 0, 0); \
        _Pragma("unroll")                                                         \
        for (int n = 0; n < 4; ++n)                                               \
            acc[n] = __builtin_amdgcn_mfma_f32_16x16x32_bf16(Al, Bh[n], acc[n], 0, 0, 0); \
    }

#pragma unroll 2
    for (int s = 0; s < NSTEP; s += 2) {
        // prefetch step s+1 into set1
        A1h = ah[(size_t)(s + 1) * 64]; A1l = al[(size_t)(s + 1) * 64];
#pragma unroll
        for (int n = 0; n < 4; ++n) {
            B1h[n] = bh[(size_t)((s + 1) * 8 + n) * 64];
            B1l[n] = bl[(size_t)((s + 1) * 8 + n) * 64];
        }
        DO_MFMA(A0h, A0l, B0h, B0l);
        // prefetch step s+2 into set0
        if (s + 2 < NSTEP) {
            A0h = ah[(size_t)(s + 2) * 64]; A0l = al[(size_t)(s + 2) * 64];
#pragma unroll
            for (int n = 0; n < 4; ++n) {
                B0h[n] = bh[(size_t)((s + 2) * 8 + n) * 64];
                B0l[n] = bl[(size_t)((s + 2) * 8 + n) * 64];
            }
        }
        DO_MFMA(A1h, A1l, B1h, B1l);
    }
#undef DO_MFMA

    // ---- epilogue: transpose through LDS for coalesced stores ----
#pragma unroll
    for (int n = 0; n < 4; ++n) {
        int o = wave_n * 64 + n * 16 + l15;
#pragma unroll
        for (int rr = 0; rr < 4; ++rr) {
            int px = wave_m * 16 + lhi * 4 + rr;
            epi[o * 33 + px] = acc[n][rr];
        }
    }
    __syncthreads();
    int p_blk = q0 + blk * 32;              // 32 px contiguous within one h-row
    int b = p_blk >> 14, hw = p_blk & 16383;
    float* ob = out + (size_t)b * CO * HW + hw;
    for (int i = tid; i < CO * 32; i += 256) {
        int o  = i >> 5;
        int px = i & 31;
        ob[(size_t)o * HW + px] = epi[o * 33 + px] + b_main[o];
    }
}

// ---------------------------------------------------------------------------
extern "C" void kernel_launch(void* const* d_in, const int* in_sizes, int n_in,
                              void* d_out, int out_size, void* d_ws, size_t ws_size,
                              hipStream_t stream) {
    const float* x      = (const float*)d_in[0];
    const float* w_off  = (const float*)d_in[1];
    const float* b_off  = (const float*)d_in[2];
    const float* w_main = (const float*)d_in[3];
    const float* b_main = (const float*)d_in[4];
    float* out = (float*)d_out;

    // workspace layout (bytes):
    //  xt 33,554,432 | coords 4,718,592 | woff_t 82,944 | wfrag 2x294,912
    //  | afrag (chunked A fragments, hi+lo)
    char* base = (char*)d_ws;
    float*  xt     = (float*)base;
    float2* coords = (float2*)(base + 33554432);
    float*  woff_t = (float*)(base + 33554432 + 4718592);
    unsigned short* wfh = (unsigned short*)(base + 33554432 + 4718592 + 82944);
    unsigned short* wfl = wfh + (size_t)CO * KTOT;
    size_t fixed_b = 33554432 + 4718592 + 82944 + 2 * (size_t)CO * KTOT * 2;
    unsigned short* afrag = (unsigned short*)(base + fixed_b);

    // chunk size: multiple of 2048 px; 4608 B per px (hi+lo bf16 x 1152)
    size_t avail = (ws_size > fixed_b) ? (ws_size - fixed_b) : 0;
    long long maxpx = (long long)(avail / 4608);
    int chunk = (int)((maxpx / 2048) * 2048);
    if (chunk > Bb * HW) chunk = Bb * HW;
    if (chunk < 2048) chunk = 2048;          // minimum footprint fallback
    unsigned short* afh = afrag;
    unsigned short* afl = afrag + (size_t)chunk * KTOT;

    k_transpose<<<dim3(HW / 32, CI / 32, Bb), dim3(32, 8), 0, stream>>>(x, xt);
    k_weights<<<576, 256, 0, stream>>>(w_off, w_main, woff_t, wfh, wfl);
    k_offsets<<<Bb * Hh * (Ww / 16), 256, 0, stream>>>(xt, woff_t, b_off, coords);
    for (int q0 = 0; q0 < Bb * HW; q0 += chunk) {
        int np = Bb * HW - q0; if (np > chunk) np = chunk;
        k_sample<<<(np / 16) * 9 / 4, 256, 0, stream>>>(xt, coords, afh, afl, q0);
        k_gemm<<<np / 32, 256, 0, stream>>>(afh, afl, wfh, wfl, b_main, out, q0);
    }
}

// Round 9
// 349.727 us; speedup vs baseline: 3.5623x; 1.3668x over previous
//
#include <hip/hip_runtime.h>
#include <cstddef>

// Problem constants (match reference)
#define Bb   4
#define CI   128
#define CO   128
#define Hh   128
#define Ww   128
#define HW   (Hh*Ww)
#define NOFF 18      // 2*K*K
#define NTAP 9       // K*K
#define KTOT (NTAP*CI)   // 1152
#define NSTEP 36     // K-steps of 32: NTAP*4

typedef short short8 __attribute__((ext_vector_type(8)));
typedef float floatx4 __attribute__((ext_vector_type(4)));

// bf16 RNE split helpers (no NaN/inf in this data)
__device__ inline unsigned short bf16_rne_bits(float f) {
    unsigned u = __float_as_uint(f);
    unsigned r = u + 0x7FFFu + ((u >> 16) & 1u);
    return (unsigned short)(r >> 16);
}
__device__ inline float bf16_bits_to_f32(unsigned short h) {
    return __uint_as_float((unsigned)h << 16);
}

// ---------------------------------------------------------------------------
// K0: transpose x NCHW -> NHWC
// ---------------------------------------------------------------------------
__global__ __launch_bounds__(256) void k_transpose(const float* __restrict__ x,
                                                   float* __restrict__ xt) {
    __shared__ float tile[32][33];
    int b  = blockIdx.z;
    int c0 = blockIdx.y * 32;
    int p0 = blockIdx.x * 32;
    int tx = threadIdx.x;
    int ty = threadIdx.y;
    const float* xb  = x  + (size_t)b * CI * HW;
    float*       xtb = xt + (size_t)b * HW * CI;
#pragma unroll
    for (int i = 0; i < 4; ++i) {
        int c = c0 + ty + 8 * i;
        tile[ty + 8 * i][tx] = xb[(size_t)c * HW + p0 + tx];
    }
    __syncthreads();
#pragma unroll
    for (int i = 0; i < 4; ++i) {
        int p = p0 + ty + 8 * i;
        xtb[(size_t)p * CI + c0 + tx] = tile[tx][ty + 8 * i];
    }
}

// ---------------------------------------------------------------------------
// K0b: weight layout transforms, all fragment-linear bf16 hi/lo.
//  wofrag (offset conv, N padded to 32):
//    i = ((t*4+ks)*2 + nt)*512 + l*8 + j
//    value = w_off[(oc*128+c)*9 + t], oc = nt*16+(l&15) (0 if oc>=18),
//    c = ks*32+(l>>4)*8+j
//  wfrag (main conv): i = ((t*4+ks)*8 + g)*512 + l*8 + j ;
//    value = w_main[o = g*16+(l&15)][c = ks*32+(l>>4)*8+j][tap t]
// ---------------------------------------------------------------------------
__global__ __launch_bounds__(256) void k_weights(const float* __restrict__ w_off,
                                                 const float* __restrict__ w_main,
                                                 unsigned short* __restrict__ wofh,
                                                 unsigned short* __restrict__ wofl,
                                                 unsigned short* __restrict__ wfrag_hi,
                                                 unsigned short* __restrict__ wfrag_lo) {
    int idx = blockIdx.x * 256 + threadIdx.x;
    int stride = gridDim.x * 256;
    for (int i = idx; i < 9 * 4 * 2 * 512; i += stride) {
        int j  = i & 7;
        int l  = (i >> 3) & 63;
        int nt = (i >> 9) & 1;
        int ks = (i >> 10) & 3;
        int t  = i >> 12;                       // 0..8  (= ky*3+kx)
        int oc = nt * 16 + (l & 15);
        int c  = ks * 32 + (l >> 4) * 8 + j;
        float f = (oc < NOFF) ? w_off[(oc * CI + c) * 9 + t] : 0.f;
        unsigned short hb = bf16_rne_bits(f);
        wofh[i] = hb;
        wofl[i] = bf16_rne_bits(f - bf16_bits_to_f32(hb));
    }
    for (int i = idx; i < CO * KTOT; i += stride) {
        int j  = i & 7;
        int l  = (i >> 3) & 63;
        int g  = (i >> 9) & 7;
        int ks = (i >> 12) & 3;
        int t  = i >> 14;
        int o  = g * 16 + (l & 15);
        int c  = ks * 32 + (l >> 4) * 8 + j;
        float f = w_main[(o * CI + c) * 9 + t];
        unsigned short hb = bf16_rne_bits(f);
        wfrag_hi[i] = hb;
        wfrag_lo[i] = bf16_rne_bits(f - bf16_bits_to_f32(hb));
    }
}

// ---------------------------------------------------------------------------
// K1: offset conv via split-bf16 MFMA + cumsum + sample coords.
// Block = 32 px x 32 oc(18 valid), 4 waves = 2 M-tiles x 2 N-tiles.
// Patch (3 rows x 34 cols x 128 ch) staged in LDS as bf16 hi/lo,
// XOR-swizzled by (col&7)<<4 (identical scheme to validated k_main/k_gemm).
// 36 K-steps x 3 products; even/odd ks accumulators to break the MFMA chain.
// ---------------------------------------------------------------------------
__global__ __launch_bounds__(256, 2) void k_offsets(const float* __restrict__ xt,
                                                    const unsigned short* __restrict__ wofh,
                                                    const unsigned short* __restrict__ wofl,
                                                    const float* __restrict__ b_off,
                                                    float2* __restrict__ coords) {
    __shared__ __align__(16) unsigned short ph[3 * 34 * 128];  // 26,112 B
    __shared__ __align__(16) unsigned short pl[3 * 34 * 128];  // 26,112 B
    __shared__ float raw[32][19];                              //  2,432 B
    int blk = blockIdx.x;
    int wt  = blk & 3;
    int h   = (blk >> 2) & 127;
    int b   = blk >> 9;
    int w0  = wt * 32;
    int tid  = threadIdx.x;
    int lane = tid & 63;
    int wave = tid >> 6;

    // ---- stage patch: 3 x 34 x 128 ch, float2 per thread-task ----
    for (int i = tid; i < 3 * 34 * 64; i += 256) {
        int c2  = i & 63;
        int col = (i >> 6) % 34;
        int r   = i / (34 * 64);
        int gy  = h - 1 + r;
        int gx  = w0 - 1 + col;
        float2 v = make_float2(0.f, 0.f);
        if (gy >= 0 && gy < Hh && gx >= 0 && gx < Ww)
            v = *(const float2*)(xt + (((size_t)b * Hh + gy) * Ww + gx) * CI + c2 * 2);
        unsigned short h0 = bf16_rne_bits(v.x);
        unsigned short h1 = bf16_rne_bits(v.y);
        unsigned l0 = bf16_rne_bits(v.x - bf16_bits_to_f32(h0));
        unsigned l1 = bf16_rne_bits(v.y - bf16_bits_to_f32(h1));
        int byte = (((r * 34 + col) * 128) + c2 * 2) * 2;
        byte ^= (col & 7) << 4;
        *(unsigned*)((char*)ph + byte) = (unsigned)h0 | ((unsigned)h1 << 16);
        *(unsigned*)((char*)pl + byte) = l0 | (l1 << 16);
    }
    __syncthreads();

    // ---- MFMA: wave = (m = px-tile, nt = oc-tile) ----
    int m   = wave & 1;
    int nt  = wave >> 1;
    int l15 = lane & 15, lhi = lane >> 4;
    floatx4 accE = (floatx4){0.f, 0.f, 0.f, 0.f};
    floatx4 accO = (floatx4){0.f, 0.f, 0.f, 0.f};
    const short8* bhp = (const short8*)wofh;
    const short8* blp = (const short8*)wofl;
#pragma unroll
    for (int t = 0; t < 9; ++t) {
        int ki = t / 3, kj = t % 3;
        int colb = m * 16 + l15 + kj;          // patch col for this lane
        int rowoff = (ki * 34 + colb) * 256;
#pragma unroll
        for (int ks = 0; ks < 4; ++ks) {
            int abyte = (rowoff + ks * 64 + lhi * 16) ^ ((colb & 7) << 4);
            short8 Ah = *(const short8*)((char*)ph + abyte);
            short8 Al = *(const short8*)((char*)pl + abyte);
            size_t bi = (size_t)((t * 4 + ks) * 2 + nt) * 64 + lane;
            short8 Bh = bhp[bi];
            short8 Bl = blp[bi];
            floatx4& a = (ks & 1) ? accO : accE;
            a = __builtin_amdgcn_mfma_f32_16x16x32_bf16(Ah, Bh, a, 0, 0, 0);
            a = __builtin_amdgcn_mfma_f32_16x16x32_bf16(Ah, Bl, a, 0, 0, 0);
            a = __builtin_amdgcn_mfma_f32_16x16x32_bf16(Al, Bh, a, 0, 0, 0);
        }
    }
    int oc = nt * 16 + l15;
    if (oc < NOFF) {
        float bo = b_off[oc];
#pragma unroll
        for (int r = 0; r < 4; ++r) {
            int px = m * 16 + lhi * 4 + r;
            raw[px][oc] = (accE[r] + accO[r]) + bo;
        }
    }
    __syncthreads();

    // ---- cumsum + coordinate math ----
    for (int i = tid; i < 32 * NTAP; i += 256) {
        int px = i / NTAP;
        int t  = i % NTAP;
        int ki = t / 3, kj = t % 3;
        float offx = 0.f, offy = 0.f;
        for (int q = 0; q <= ki; ++q) offx += raw[px][q * 6 + kj * 2 + 0];
        for (int q = 0; q <= kj; ++q) offy += raw[px][ki * 6 + q * 2 + 1];
        int wg = w0 + px;
        float xg = -1.0f + 2.0f * (float)wg / 127.0f;
        float yg = -1.0f + 2.0f * (float)h  / 127.0f;
        float gx = xg + offx;
        float gy = yg + offy;
        float ix = ((gx + 1.0f) * (float)Ww - 1.0f) * 0.5f;
        float iy = ((gy + 1.0f) * (float)Hh - 1.0f) * 0.5f;
        coords[(((size_t)b * Hh + h) * Ww + wg) * NTAP + t] = make_float2(ix, iy);
    }
}

// ---------------------------------------------------------------------------
// K2a: k_sample — bilinear sample + bf16 hi/lo split, written FRAGMENT-LINEAR.
// Wave = 16 px x 1 tap; lane=(px, c-octet). No LDS, no barriers: pure TLP.
//  afrag idx (short8 units): (Pl*36 + tap*4 + ks)*64 + lane
// ---------------------------------------------------------------------------
__global__ __launch_bounds__(256) void k_sample(const float* __restrict__ xt,
                                                const float2* __restrict__ coords,
                                                unsigned short* __restrict__ afh,
                                                unsigned short* __restrict__ afl,
                                                int q0) {
    int nb = gridDim.x;
    int blkid = blockIdx.x;
    int cpx = nb >> 3;
    blkid = (blkid & 7) * cpx + (blkid >> 3);   // XCD-contiguous remap (nb%8==0)
    int task = blkid * 4 + (threadIdx.x >> 6);
    int lane = threadIdx.x & 63;
    int Pl   = task / 9;
    int tap  = task - Pl * 9;
    int r = lane & 15, q = lane >> 4;
    int p = q0 + Pl * 16 + r;          // global pixel
    int b = p >> 14;

    float2 co = coords[(size_t)p * NTAP + tap];
    float ix = co.x, iy = co.y;
    float fx0 = floorf(ix), fy0 = floorf(iy);
    int x0 = (int)fx0, y0 = (int)fy0;
    int x1 = x0 + 1,   y1 = y0 + 1;
    float wx1 = ix - fx0, wy1 = iy - fy0;
    float wx0 = 1.f - wx1, wy0 = 1.f - wy1;
    bool vx0 = (x0 >= 0) & (x0 < Ww);
    bool vx1 = (x1 >= 0) & (x1 < Ww);
    bool vy0 = (y0 >= 0) & (y0 < Hh);
    bool vy1 = (y1 >= 0) & (y1 < Hh);
    int cx0 = min(max(x0, 0), Ww - 1), cx1 = min(max(x1, 0), Ww - 1);
    int cy0 = min(max(y0, 0), Hh - 1), cy1 = min(max(y1, 0), Hh - 1);
    float w00 = (vy0 && vx0) ? wy0 * wx0 : 0.f;
    float w01 = (vy0 && vx1) ? wy0 * wx1 : 0.f;
    float w10 = (vy1 && vx0) ? wy1 * wx0 : 0.f;
    float w11 = (vy1 && vx1) ? wy1 * wx1 : 0.f;

    const float* xb  = xt + (size_t)b * HW * CI + q * 8;
    const float* r00 = xb + ((size_t)cy0 * Ww + cx0) * CI;
    const float* r01 = xb + ((size_t)cy0 * Ww + cx1) * CI;
    const float* r10 = xb + ((size_t)cy1 * Ww + cx0) * CI;
    const float* r11 = xb + ((size_t)cy1 * Ww + cx1) * CI;
    size_t obase = ((size_t)(Pl * 36 + tap * 4) * 64 + lane) * 8;

#pragma unroll
    for (int ks = 0; ks < 4; ++ks) {
        int c = ks * 32;
        float4 a0 = *(const float4*)(r00 + c), a1 = *(const float4*)(r00 + c + 4);
        float4 b0 = *(const float4*)(r01 + c), b1 = *(const float4*)(r01 + c + 4);
        float4 c0 = *(const float4*)(r10 + c), c1 = *(const float4*)(r10 + c + 4);
        float4 d0 = *(const float4*)(r11 + c), d1 = *(const float4*)(r11 + c + 4);
        float v[8];
        v[0] = w00 * a0.x + w01 * b0.x + w10 * c0.x + w11 * d0.x;
        v[1] = w00 * a0.y + w01 * b0.y + w10 * c0.y + w11 * d0.y;
        v[2] = w00 * a0.z + w01 * b0.z + w10 * c0.z + w11 * d0.z;
        v[3] = w00 * a0.w + w01 * b0.w + w10 * c0.w + w11 * d0.w;
        v[4] = w00 * a1.x + w01 * b1.x + w10 * c1.x + w11 * d1.x;
        v[5] = w00 * a1.y + w01 * b1.y + w10 * c1.y + w11 * d1.y;
        v[6] = w00 * a1.z + w01 * b1.z + w10 * c1.z + w11 * d1.z;
        v[7] = w00 * a1.w + w01 * b1.w + w10 * c1.w + w11 * d1.w;
        short8 hi, lo;
#pragma unroll
        for (int j = 0; j < 8; ++j) {
            unsigned short hb = bf16_rne_bits(v[j]);
            hi[j] = (short)hb;
            lo[j] = (short)bf16_rne_bits(v[j] - bf16_bits_to_f32(hb));
        }
        *(short8*)(afh + obase + (size_t)ks * 512) = hi;
        *(short8*)(afl + obase + (size_t)ks * 512) = lo;
    }
}

// ---------------------------------------------------------------------------
// K2b: k_gemm — register GEMM on pre-sampled fragments. Block = 32px x 128o,
// 4 waves (2m x 2n), wave = 16px x 64o. 36 K-steps, ping-pong prefetch.
// All loads are contiguous 1KB wave-loads; no LDS/barriers in main loop.
// ---------------------------------------------------------------------------
__global__ __launch_bounds__(256, 2) void k_gemm(const unsigned short* __restrict__ afh,
                                                 const unsigned short* __restrict__ afl,
                                                 const unsigned short* __restrict__ wfh,
                                                 const unsigned short* __restrict__ wfl,
                                                 const float* __restrict__ b_main,
                                                 float* __restrict__ out, int q0) {
    __shared__ __align__(16) float epi[CO * 33];   // 16,896 B (epilogue only)
    int nb = gridDim.x;
    int cpx = nb >> 3;
    int blk = blockIdx.x;
    blk = (blk & 7) * cpx + (blk >> 3);            // XCD remap (nb%8==0)
    int tid = threadIdx.x, lane = tid & 63, wave = tid >> 6;
    int wave_n = wave & 1, wave_m = wave >> 1;
    int l15 = lane & 15, lhi = lane >> 4;
    int P = blk * 2 + wave_m;                      // local 16-px tile

    const short8* ah = (const short8*)afh + (size_t)P * NSTEP * 64 + lane;
    const short8* al = (const short8*)afl + (size_t)P * NSTEP * 64 + lane;
    const short8* bh = (const short8*)wfh + (size_t)wave_n * 4 * 64 + lane;
    const short8* bl = (const short8*)wfl + (size_t)wave_n * 4 * 64 + lane;

    floatx4 acc[4];
#pragma unroll
    for (int n = 0; n < 4; ++n) acc[n] = (floatx4){0.f, 0.f, 0.f, 0.f};

    short8 A0h, A0l, B0h[4], B0l[4], A1h, A1l, B1h[4], B1l[4];
    A0h = ah[0]; A0l = al[0];
#pragma unroll
    for (int n = 0; n < 4; ++n) { B0h[n] = bh[(size_t)n * 64]; B0l[n] = bl[(size_t)n * 64]; }

#define DO_MFMA(Ah, Al, Bh, Bl)                                                   \
    {                                                                             \
        _Pragma("unroll")                                                         \
        for (int n = 0; n < 4; ++n)                                               \
            acc[n] = __builtin_amdgcn_mfma_f32_16x16x32_bf16(Ah, Bh[n], acc[n], 0, 0, 0); \
        _Pragma("unroll")                                                         \
        for (int n = 0; n < 4; ++n)                                               \
            acc[n] = __builtin_amdgcn_mfma_f32_16x16x32_bf16(Ah, Bl[n], acc[n], 0, 0, 0); \
        _Pragma("unroll")                                                         \
        for (int n = 0; n < 4; ++n)                                               \
            acc[n] = __builtin_amdgcn_mfma_f32_16x16x32_bf16(Al, Bh[n], acc[n], 0, 0, 0); \
    }

#pragma unroll 2
    for (int s = 0; s < NSTEP; s += 2) {
        A1h = ah[(size_t)(s + 1) * 64]; A1l = al[(size_t)(s + 1) * 64];
#pragma unroll
        for (int n = 0; n < 4; ++n) {
            B1h[n] = bh[(size_t)((s + 1) * 8 + n) * 64];
            B1l[n] = bl[(size_t)((s + 1) * 8 + n) * 64];
        }
        DO_MFMA(A0h, A0l, B0h, B0l);
        if (s + 2 < NSTEP) {
            A0h = ah[(size_t)(s + 2) * 64]; A0l = al[(size_t)(s + 2) * 64];
#pragma unroll
            for (int n = 0; n < 4; ++n) {
                B0h[n] = bh[(size_t)((s + 2) * 8 + n) * 64];
                B0l[n] = bl[(size_t)((s + 2) * 8 + n) * 64];
            }
        }
        DO_MFMA(A1h, A1l, B1h, B1l);
    }
#undef DO_MFMA

    // ---- epilogue: transpose through LDS for coalesced stores ----
#pragma unroll
    for (int n = 0; n < 4; ++n) {
        int o = wave_n * 64 + n * 16 + l15;
#pragma unroll
        for (int rr = 0; rr < 4; ++rr) {
            int px = wave_m * 16 + lhi * 4 + rr;
            epi[o * 33 + px] = acc[n][rr];
        }
    }
    __syncthreads();
    int p_blk = q0 + blk * 32;              // 32 px contiguous within one h-row
    int b = p_blk >> 14, hw = p_blk & 16383;
    float* ob = out + (size_t)b * CO * HW + hw;
    for (int i = tid; i < CO * 32; i += 256) {
        int o  = i >> 5;
        int px = i & 31;
        ob[(size_t)o * HW + px] = epi[o * 33 + px] + b_main[o];
    }
}

// ---------------------------------------------------------------------------
extern "C" void kernel_launch(void* const* d_in, const int* in_sizes, int n_in,
                              void* d_out, int out_size, void* d_ws, size_t ws_size,
                              hipStream_t stream) {
    const float* x      = (const float*)d_in[0];
    const float* w_off  = (const float*)d_in[1];
    const float* b_off  = (const float*)d_in[2];
    const float* w_main = (const float*)d_in[3];
    const float* b_main = (const float*)d_in[4];
    float* out = (float*)d_out;

    // workspace layout (bytes):
    //  xt 33,554,432 | coords 4,718,592 | wofrag 2x73,728 | wfrag 2x294,912
    //  | afrag (chunked A fragments, hi+lo)
    char* base = (char*)d_ws;
    float*  xt     = (float*)base;
    float2* coords = (float2*)(base + 33554432);
    unsigned short* wofh = (unsigned short*)(base + 33554432 + 4718592);
    unsigned short* wofl = wofh + 9 * 4 * 2 * 512;
    unsigned short* wfh  = wofl + 9 * 4 * 2 * 512;
    unsigned short* wfl  = wfh + (size_t)CO * KTOT;
    size_t fixed_b = 33554432 + 4718592 + 2 * (9 * 4 * 2 * 512) * 2
                   + 2 * (size_t)CO * KTOT * 2;
    unsigned short* afrag = (unsigned short*)(base + fixed_b);

    // chunk size: multiple of 2048 px; 4608 B per px (hi+lo bf16 x 1152)
    size_t avail = (ws_size > fixed_b) ? (ws_size - fixed_b) : 0;
    long long maxpx = (long long)(avail / 4608);
    int chunk = (int)((maxpx / 2048) * 2048);
    if (chunk > Bb * HW) chunk = Bb * HW;
    if (chunk < 2048) chunk = 2048;          // minimum footprint fallback
    unsigned short* afh = afrag;
    unsigned short* afl = afrag + (size_t)chunk * KTOT;

    k_transpose<<<dim3(HW / 32, CI / 32, Bb), dim3(32, 8), 0, stream>>>(x, xt);
    k_weights<<<576, 256, 0, stream>>>(w_off, w_main, wofh, wofl, wfh, wfl);
    k_offsets<<<Bb * Hh * (Ww / 32), 256, 0, stream>>>(xt, wofh, wofl, b_off, coords);
    for (int q0 = 0; q0 < Bb * HW; q0 += chunk) {
        int np = Bb * HW - q0; if (np > chunk) np = chunk;
        k_sample<<<(np / 16) * 9 / 4, 256, 0, stream>>>(xt, coords, afh, afl, q0);
        k_gemm<<<np / 32, 256, 0, stream>>>(afh, afl, wfh, wfl, b_main, out, q0);
    }
}

// Round 10
// 333.907 us; speedup vs baseline: 3.7311x; 1.0474x over previous
//
#include <hip/hip_runtime.h>
#include <cstddef>

// Problem constants (match reference)
#define Bb   4
#define CI   128
#define CO   128
#define Hh   128
#define Ww   128
#define HW   (Hh*Ww)
#define NOFF 18      // 2*K*K
#define NTAP 9       // K*K
#define KTOT (NTAP*CI)   // 1152
#define NSTEP 36     // K-steps of 32: NTAP*4

typedef short short8 __attribute__((ext_vector_type(8)));
typedef float floatx4 __attribute__((ext_vector_type(4)));

// bf16 RNE split helpers (no NaN/inf in this data)
__device__ inline unsigned short bf16_rne_bits(float f) {
    unsigned u = __float_as_uint(f);
    unsigned r = u + 0x7FFFu + ((u >> 16) & 1u);
    return (unsigned short)(r >> 16);
}
__device__ inline float bf16_bits_to_f32(unsigned short h) {
    return __uint_as_float((unsigned)h << 16);
}

// ---------------------------------------------------------------------------
// K0: transpose x NCHW -> NHWC
// ---------------------------------------------------------------------------
__global__ __launch_bounds__(256) void k_transpose(const float* __restrict__ x,
                                                   float* __restrict__ xt) {
    __shared__ float tile[32][33];
    int b  = blockIdx.z;
    int c0 = blockIdx.y * 32;
    int p0 = blockIdx.x * 32;
    int tx = threadIdx.x;
    int ty = threadIdx.y;
    const float* xb  = x  + (size_t)b * CI * HW;
    float*       xtb = xt + (size_t)b * HW * CI;
#pragma unroll
    for (int i = 0; i < 4; ++i) {
        int c = c0 + ty + 8 * i;
        tile[ty + 8 * i][tx] = xb[(size_t)c * HW + p0 + tx];
    }
    __syncthreads();
#pragma unroll
    for (int i = 0; i < 4; ++i) {
        int p = p0 + ty + 8 * i;
        xtb[(size_t)p * CI + c0 + tx] = tile[tx][ty + 8 * i];
    }
}

// ---------------------------------------------------------------------------
// K0b: weight layout transforms, all fragment-linear bf16 hi/lo.
//  wofrag (offset conv, N padded to 32):
//    i = ((t*4+ks)*2 + nt)*512 + l*8 + j
//    value = w_off[(oc*128+c)*9 + t], oc = nt*16+(l&15) (0 if oc>=18),
//    c = ks*32+(l>>4)*8+j
//  wfrag (main conv): i = ((t*4+ks)*8 + g)*512 + l*8 + j ;
//    value = w_main[o = g*16+(l&15)][c = ks*32+(l>>4)*8+j][tap t]
// ---------------------------------------------------------------------------
__global__ __launch_bounds__(256) void k_weights(const float* __restrict__ w_off,
                                                 const float* __restrict__ w_main,
                                                 unsigned short* __restrict__ wofh,
                                                 unsigned short* __restrict__ wofl,
                                                 unsigned short* __restrict__ wfrag_hi,
                                                 unsigned short* __restrict__ wfrag_lo) {
    int idx = blockIdx.x * 256 + threadIdx.x;
    int stride = gridDim.x * 256;
    for (int i = idx; i < 9 * 4 * 2 * 512; i += stride) {
        int j  = i & 7;
        int l  = (i >> 3) & 63;
        int nt = (i >> 9) & 1;
        int ks = (i >> 10) & 3;
        int t  = i >> 12;                       // 0..8  (= ky*3+kx)
        int oc = nt * 16 + (l & 15);
        int c  = ks * 32 + (l >> 4) * 8 + j;
        float f = (oc < NOFF) ? w_off[(oc * CI + c) * 9 + t] : 0.f;
        unsigned short hb = bf16_rne_bits(f);
        wofh[i] = hb;
        wofl[i] = bf16_rne_bits(f - bf16_bits_to_f32(hb));
    }
    for (int i = idx; i < CO * KTOT; i += stride) {
        int j  = i & 7;
        int l  = (i >> 3) & 63;
        int g  = (i >> 9) & 7;
        int ks = (i >> 12) & 3;
        int t  = i >> 14;
        int o  = g * 16 + (l & 15);
        int c  = ks * 32 + (l >> 4) * 8 + j;
        float f = w_main[(o * CI + c) * 9 + t];
        unsigned short hb = bf16_rne_bits(f);
        wfrag_hi[i] = hb;
        wfrag_lo[i] = bf16_rne_bits(f - bf16_bits_to_f32(hb));
    }
}

// ---------------------------------------------------------------------------
// K1: offset conv via split-bf16 MFMA + cumsum + sample coords.
// Block = 32 px x 32 oc(18 valid), 4 waves = 2 M-tiles x 2 N-tiles.
// ---------------------------------------------------------------------------
__global__ __launch_bounds__(256, 2) void k_offsets(const float* __restrict__ xt,
                                                    const unsigned short* __restrict__ wofh,
                                                    const unsigned short* __restrict__ wofl,
                                                    const float* __restrict__ b_off,
                                                    float2* __restrict__ coords) {
    __shared__ __align__(16) unsigned short ph[3 * 34 * 128];  // 26,112 B
    __shared__ __align__(16) unsigned short pl[3 * 34 * 128];  // 26,112 B
    __shared__ float raw[32][19];                              //  2,432 B
    int blk = blockIdx.x;
    int wt  = blk & 3;
    int h   = (blk >> 2) & 127;
    int b   = blk >> 9;
    int w0  = wt * 32;
    int tid  = threadIdx.x;
    int lane = tid & 63;
    int wave = tid >> 6;

    // ---- stage patch: 3 x 34 x 128 ch, float2 per thread-task ----
    for (int i = tid; i < 3 * 34 * 64; i += 256) {
        int c2  = i & 63;
        int col = (i >> 6) % 34;
        int r   = i / (34 * 64);
        int gy  = h - 1 + r;
        int gx  = w0 - 1 + col;
        float2 v = make_float2(0.f, 0.f);
        if (gy >= 0 && gy < Hh && gx >= 0 && gx < Ww)
            v = *(const float2*)(xt + (((size_t)b * Hh + gy) * Ww + gx) * CI + c2 * 2);
        unsigned short h0 = bf16_rne_bits(v.x);
        unsigned short h1 = bf16_rne_bits(v.y);
        unsigned l0 = bf16_rne_bits(v.x - bf16_bits_to_f32(h0));
        unsigned l1 = bf16_rne_bits(v.y - bf16_bits_to_f32(h1));
        int byte = (((r * 34 + col) * 128) + c2 * 2) * 2;
        byte ^= (col & 7) << 4;
        *(unsigned*)((char*)ph + byte) = (unsigned)h0 | ((unsigned)h1 << 16);
        *(unsigned*)((char*)pl + byte) = l0 | (l1 << 16);
    }
    __syncthreads();

    // ---- MFMA: wave = (m = px-tile, nt = oc-tile) ----
    int m   = wave & 1;
    int nt  = wave >> 1;
    int l15 = lane & 15, lhi = lane >> 4;
    floatx4 accE = (floatx4){0.f, 0.f, 0.f, 0.f};
    floatx4 accO = (floatx4){0.f, 0.f, 0.f, 0.f};
    const short8* bhp = (const short8*)wofh;
    const short8* blp = (const short8*)wofl;
#pragma unroll
    for (int t = 0; t < 9; ++t) {
        int ki = t / 3, kj = t % 3;
        int colb = m * 16 + l15 + kj;          // patch col for this lane
        int rowoff = (ki * 34 + colb) * 256;
#pragma unroll
        for (int ks = 0; ks < 4; ++ks) {
            int abyte = (rowoff + ks * 64 + lhi * 16) ^ ((colb & 7) << 4);
            short8 Ah = *(const short8*)((char*)ph + abyte);
            short8 Al = *(const short8*)((char*)pl + abyte);
            size_t bi = (size_t)((t * 4 + ks) * 2 + nt) * 64 + lane;
            short8 Bh = bhp[bi];
            short8 Bl = blp[bi];
            floatx4& a = (ks & 1) ? accO : accE;
            a = __builtin_amdgcn_mfma_f32_16x16x32_bf16(Ah, Bh, a, 0, 0, 0);
            a = __builtin_amdgcn_mfma_f32_16x16x32_bf16(Ah, Bl, a, 0, 0, 0);
            a = __builtin_amdgcn_mfma_f32_16x16x32_bf16(Al, Bh, a, 0, 0, 0);
        }
    }
    int oc = nt * 16 + l15;
    if (oc < NOFF) {
        float bo = b_off[oc];
#pragma unroll
        for (int r = 0; r < 4; ++r) {
            int px = m * 16 + lhi * 4 + r;
            raw[px][oc] = (accE[r] + accO[r]) + bo;
        }
    }
    __syncthreads();

    // ---- cumsum + coordinate math ----
    for (int i = tid; i < 32 * NTAP; i += 256) {
        int px = i / NTAP;
        int t  = i % NTAP;
        int ki = t / 3, kj = t % 3;
        float offx = 0.f, offy = 0.f;
        for (int q = 0; q <= ki; ++q) offx += raw[px][q * 6 + kj * 2 + 0];
        for (int q = 0; q <= kj; ++q) offy += raw[px][ki * 6 + q * 2 + 1];
        int wg = w0 + px;
        float xg = -1.0f + 2.0f * (float)wg / 127.0f;
        float yg = -1.0f + 2.0f * (float)h  / 127.0f;
        float gx = xg + offx;
        float gy = yg + offy;
        float ix = ((gx + 1.0f) * (float)Ww - 1.0f) * 0.5f;
        float iy = ((gy + 1.0f) * (float)Hh - 1.0f) * 0.5f;
        coords[(((size_t)b * Hh + h) * Ww + wg) * NTAP + t] = make_float2(ix, iy);
    }
}

// ---------------------------------------------------------------------------
// K2a: k_sample — bilinear sample + bf16 hi/lo split, written FRAGMENT-LINEAR.
// Wave = 16 px x 1 tap; lane=(px, c-octet). No LDS, no barriers: pure TLP.
//  afrag idx (short8 units): (Pl*36 + tap*4 + ks)*64 + lane
// ---------------------------------------------------------------------------
__global__ __launch_bounds__(256) void k_sample(const float* __restrict__ xt,
                                                const float2* __restrict__ coords,
                                                unsigned short* __restrict__ afh,
                                                unsigned short* __restrict__ afl,
                                                int q0) {
    int nb = gridDim.x;
    int blkid = blockIdx.x;
    int cpx = nb >> 3;
    blkid = (blkid & 7) * cpx + (blkid >> 3);   // XCD-contiguous remap (nb%8==0)
    int task = blkid * 4 + (threadIdx.x >> 6);
    int lane = threadIdx.x & 63;
    int Pl   = task / 9;
    int tap  = task - Pl * 9;
    int r = lane & 15, q = lane >> 4;
    int p = q0 + Pl * 16 + r;          // global pixel
    int b = p >> 14;

    float2 co = coords[(size_t)p * NTAP + tap];
    float ix = co.x, iy = co.y;
    float fx0 = floorf(ix), fy0 = floorf(iy);
    int x0 = (int)fx0, y0 = (int)fy0;
    int x1 = x0 + 1,   y1 = y0 + 1;
    float wx1 = ix - fx0, wy1 = iy - fy0;
    float wx0 = 1.f - wx1, wy0 = 1.f - wy1;
    bool vx0 = (x0 >= 0) & (x0 < Ww);
    bool vx1 = (x1 >= 0) & (x1 < Ww);
    bool vy0 = (y0 >= 0) & (y0 < Hh);
    bool vy1 = (y1 >= 0) & (y1 < Hh);
    int cx0 = min(max(x0, 0), Ww - 1), cx1 = min(max(x1, 0), Ww - 1);
    int cy0 = min(max(y0, 0), Hh - 1), cy1 = min(max(y1, 0), Hh - 1);
    float w00 = (vy0 && vx0) ? wy0 * wx0 : 0.f;
    float w01 = (vy0 && vx1) ? wy0 * wx1 : 0.f;
    float w10 = (vy1 && vx0) ? wy1 * wx0 : 0.f;
    float w11 = (vy1 && vx1) ? wy1 * wx1 : 0.f;

    const float* xb  = xt + (size_t)b * HW * CI + q * 8;
    const float* r00 = xb + ((size_t)cy0 * Ww + cx0) * CI;
    const float* r01 = xb + ((size_t)cy0 * Ww + cx1) * CI;
    const float* r10 = xb + ((size_t)cy1 * Ww + cx0) * CI;
    const float* r11 = xb + ((size_t)cy1 * Ww + cx1) * CI;
    size_t obase = ((size_t)(Pl * 36 + tap * 4) * 64 + lane) * 8;

#pragma unroll
    for (int ks = 0; ks < 4; ++ks) {
        int c = ks * 32;
        float4 a0 = *(const float4*)(r00 + c), a1 = *(const float4*)(r00 + c + 4);
        float4 b0 = *(const float4*)(r01 + c), b1 = *(const float4*)(r01 + c + 4);
        float4 c0 = *(const float4*)(r10 + c), c1 = *(const float4*)(r10 + c + 4);
        float4 d0 = *(const float4*)(r11 + c), d1 = *(const float4*)(r11 + c + 4);
        float v[8];
        v[0] = w00 * a0.x + w01 * b0.x + w10 * c0.x + w11 * d0.x;
        v[1] = w00 * a0.y + w01 * b0.y + w10 * c0.y + w11 * d0.y;
        v[2] = w00 * a0.z + w01 * b0.z + w10 * c0.z + w11 * d0.z;
        v[3] = w00 * a0.w + w01 * b0.w + w10 * c0.w + w11 * d0.w;
        v[4] = w00 * a1.x + w01 * b1.x + w10 * c1.x + w11 * d1.x;
        v[5] = w00 * a1.y + w01 * b1.y + w10 * c1.y + w11 * d1.y;
        v[6] = w00 * a1.z + w01 * b1.z + w10 * c1.z + w11 * d1.z;
        v[7] = w00 * a1.w + w01 * b1.w + w10 * c1.w + w11 * d1.w;
        short8 hi, lo;
#pragma unroll
        for (int j = 0; j < 8; ++j) {
            unsigned short hb = bf16_rne_bits(v[j]);
            hi[j] = (short)hb;
            lo[j] = (short)bf16_rne_bits(v[j] - bf16_bits_to_f32(hb));
        }
        *(short8*)(afh + obase + (size_t)ks * 512) = hi;
        *(short8*)(afl + obase + (size_t)ks * 512) = lo;
    }
}

// ---------------------------------------------------------------------------
// K2b: k_gemm — register GEMM on pre-sampled fragments. Block = 32px x 128o,
// 4 waves (2m x 2n), wave = 16px x 64o. 36 K-steps, ping-pong prefetch.
// All loads are contiguous 1KB wave-loads; no LDS/barriers in main loop.
// Out stores are non-temporal: write-once stream must not evict afrag/xt L3.
// ---------------------------------------------------------------------------
__global__ __launch_bounds__(256, 2) void k_gemm(const unsigned short* __restrict__ afh,
                                                 const unsigned short* __restrict__ afl,
                                                 const unsigned short* __restrict__ wfh,
                                                 const unsigned short* __restrict__ wfl,
                                                 const float* __restrict__ b_main,
                                                 float* __restrict__ out, int q0) {
    __shared__ __align__(16) float epi[CO * 33];   // 16,896 B (epilogue only)
    int nb = gridDim.x;
    int cpx = nb >> 3;
    int blk = blockIdx.x;
    blk = (blk & 7) * cpx + (blk >> 3);            // XCD remap (nb%8==0)
    int tid = threadIdx.x, lane = tid & 63, wave = tid >> 6;
    int wave_n = wave & 1, wave_m = wave >> 1;
    int l15 = lane & 15, lhi = lane >> 4;
    int P = blk * 2 + wave_m;                      // local 16-px tile

    const short8* ah = (const short8*)afh + (size_t)P * NSTEP * 64 + lane;
    const short8* al = (const short8*)afl + (size_t)P * NSTEP * 64 + lane;
    const short8* bh = (const short8*)wfh + (size_t)wave_n * 4 * 64 + lane;
    const short8* bl = (const short8*)wfl + (size_t)wave_n * 4 * 64 + lane;

    floatx4 acc[4];
#pragma unroll
    for (int n = 0; n < 4; ++n) acc[n] = (floatx4){0.f, 0.f, 0.f, 0.f};

    short8 A0h, A0l, B0h[4], B0l[4], A1h, A1l, B1h[4], B1l[4];
    A0h = ah[0]; A0l = al[0];
#pragma unroll
    for (int n = 0; n < 4; ++n) { B0h[n] = bh[(size_t)n * 64]; B0l[n] = bl[(size_t)n * 64]; }

#define DO_MFMA(Ah, Al, Bh, Bl)                                                   \
    {                                                                             \
        _Pragma("unroll")                                                         \
        for (int n = 0; n < 4; ++n)                                               \
            acc[n] = __builtin_amdgcn_mfma_f32_16x16x32_bf16(Ah, Bh[n], acc[n], 0, 0, 0); \
        _Pragma("unroll")                                                         \
        for (int n = 0; n < 4; ++n)                                               \
            acc[n] = __builtin_amdgcn_mfma_f32_16x16x32_bf16(Ah, Bl[n], acc[n], 0, 0, 0); \
        _Pragma("unroll")                                                         \
        for (int n = 0; n < 4; ++n)                                               \
            acc[n] = __builtin_amdgcn_mfma_f32_16x16x32_bf16(Al, Bh[n], acc[n], 0, 0, 0); \
    }

#pragma unroll 2
    for (int s = 0; s < NSTEP; s += 2) {
        A1h = ah[(size_t)(s + 1) * 64]; A1l = al[(size_t)(s + 1) * 64];
#pragma unroll
        for (int n = 0; n < 4; ++n) {
            B1h[n] = bh[(size_t)((s + 1) * 8 + n) * 64];
            B1l[n] = bl[(size_t)((s + 1) * 8 + n) * 64];
        }
        DO_MFMA(A0h, A0l, B0h, B0l);
        if (s + 2 < NSTEP) {
            A0h = ah[(size_t)(s + 2) * 64]; A0l = al[(size_t)(s + 2) * 64];
#pragma unroll
            for (int n = 0; n < 4; ++n) {
                B0h[n] = bh[(size_t)((s + 2) * 8 + n) * 64];
                B0l[n] = bl[(size_t)((s + 2) * 8 + n) * 64];
            }
        }
        DO_MFMA(A1h, A1l, B1h, B1l);
    }
#undef DO_MFMA

    // ---- epilogue: transpose through LDS for coalesced stores ----
#pragma unroll
    for (int n = 0; n < 4; ++n) {
        int o = wave_n * 64 + n * 16 + l15;
#pragma unroll
        for (int rr = 0; rr < 4; ++rr) {
            int px = wave_m * 16 + lhi * 4 + rr;
            epi[o * 33 + px] = acc[n][rr];
        }
    }
    __syncthreads();
    int p_blk = q0 + blk * 32;              // 32 px contiguous within one h-row
    int b = p_blk >> 14, hw = p_blk & 16383;
    float* ob = out + (size_t)b * CO * HW + hw;
    for (int i = tid; i < CO * 32; i += 256) {
        int o  = i >> 5;
        int px = i & 31;
        __builtin_nontemporal_store(epi[o * 33 + px] + b_main[o],
                                    &ob[(size_t)o * HW + px]);
    }
}

// ---------------------------------------------------------------------------
extern "C" void kernel_launch(void* const* d_in, const int* in_sizes, int n_in,
                              void* d_out, int out_size, void* d_ws, size_t ws_size,
                              hipStream_t stream) {
    const float* x      = (const float*)d_in[0];
    const float* w_off  = (const float*)d_in[1];
    const float* b_off  = (const float*)d_in[2];
    const float* w_main = (const float*)d_in[3];
    const float* b_main = (const float*)d_in[4];
    float* out = (float*)d_out;

    // workspace layout (bytes):
    //  xt 33,554,432 | coords 4,718,592 | wofrag 2x73,728 | wfrag 2x294,912
    //  | afrag (chunked A fragments, hi+lo)
    char* base = (char*)d_ws;
    float*  xt     = (float*)base;
    float2* coords = (float2*)(base + 33554432);
    unsigned short* wofh = (unsigned short*)(base + 33554432 + 4718592);
    unsigned short* wofl = wofh + 9 * 4 * 2 * 512;
    unsigned short* wfh  = wofl + 9 * 4 * 2 * 512;
    unsigned short* wfl  = wfh + (size_t)CO * KTOT;
    size_t fixed_b = 33554432 + 4718592 + 2 * (9 * 4 * 2 * 512) * 2
                   + 2 * (size_t)CO * KTOT * 2;
    unsigned short* afrag = (unsigned short*)(base + fixed_b);

    // chunk: multiple of 2048 px, capped at 32768 so the afrag working set
    // (151 MB) + xt (33.5 MB) stays L3-resident (256 MB). Same-buffer reuse
    // across chunks keeps afrag lines dirty-in-L3 (no HBM round trip).
    size_t avail = (ws_size > fixed_b) ? (ws_size - fixed_b) : 0;
    long long maxpx = (long long)(avail / 4608);
    int chunk = (int)((maxpx / 2048) * 2048);
    if (chunk > 32768) chunk = 32768;
    if (chunk < 2048) chunk = 2048;          // minimum footprint fallback
    unsigned short* afh = afrag;
    unsigned short* afl = afrag + (size_t)chunk * KTOT;

    k_transpose<<<dim3(HW / 32, CI / 32, Bb), dim3(32, 8), 0, stream>>>(x, xt);
    k_weights<<<576, 256, 0, stream>>>(w_off, w_main, wofh, wofl, wfh, wfl);
    k_offsets<<<Bb * Hh * (Ww / 32), 256, 0, stream>>>(xt, wofh, wofl, b_off, coords);
    for (int q0 = 0; q0 < Bb * HW; q0 += chunk) {
        int np = Bb * HW - q0; if (np > chunk) np = chunk;
        k_sample<<<(np / 16) * 9 / 4, 256, 0, stream>>>(xt, coords, afh, afl, q0);
        k_gemm<<<np / 32, 256, 0, stream>>>(afh, afl, wfh, wfl, b_main, out, q0);
    }
}